// Round 19
// baseline (323.695 us; speedup 1.0000x reference)
//
#include <hip/hip_runtime.h>
#include <math.h>

#define HN 16
#define SEQ 1024
#define DMODEL 1024
#define DH 64
#define SM1 1023   // S-1

typedef float  f32x4  __attribute__((ext_vector_type(4)));
typedef __bf16 bf16x8 __attribute__((ext_vector_type(8)));

// async global->LDS DMA, 16B per lane, dest = wave-uniform base + lane*16
#define GLD16(gsrc, ldst) \
    __builtin_amdgcn_global_load_lds((const __attribute__((address_space(1))) void*)(gsrc), \
                                     (__attribute__((address_space(3))) void*)(ldst), 16, 0, 0)

// ---------------------------------------------------------------
// split3: fp32 -> bf16 hi/lo planes for q,k,v in one launch.
// ---------------------------------------------------------------
__global__ __launch_bounds__(256)
void split3_kernel(const float* __restrict__ s0, __bf16* __restrict__ h0, __bf16* __restrict__ l0, int n0,
                   const float* __restrict__ s1, __bf16* __restrict__ h1, __bf16* __restrict__ l1, int n1,
                   const float* __restrict__ s2, __bf16* __restrict__ h2, __bf16* __restrict__ l2, int n2)
{
    const float* src; __bf16* hi; __bf16* lo; int nchunks;
    if (blockIdx.y == 0)      { src = s0; hi = h0; lo = l0; nchunks = n0; }
    else if (blockIdx.y == 1) { src = s1; hi = h1; lo = l1; nchunks = n1; }
    else                      { src = s2; hi = h2; lo = l2; nchunks = n2; }

    for (int i = blockIdx.x * 256 + threadIdx.x; i < nchunks; i += gridDim.x * 256) {
        float4 v0 = *(const float4*)&src[(size_t)i * 8];
        float4 v1 = *(const float4*)&src[(size_t)i * 8 + 4];
        float xa[8] = {v0.x, v0.y, v0.z, v0.w, v1.x, v1.y, v1.z, v1.w};
        bf16x8 h8, l8;
#pragma unroll
        for (int e = 0; e < 8; ++e) {
            __bf16 hb = (__bf16)xa[e];
            h8[e] = hb;
            l8[e] = (__bf16)(xa[e] - (float)hb);
        }
        *(bf16x8*)&hi[(size_t)i * 8] = h8;
        *(bf16x8*)&lo[(size_t)i * 8] = l8;
    }
}

// ---------------------------------------------------------------
// splitT4: W[1024][1024] fp32 -> transposed hi/lo planes, 4 weights.
// ---------------------------------------------------------------
__global__ __launch_bounds__(256)
void splitT4_kernel(const float* __restrict__ W0, __bf16* __restrict__ th0, __bf16* __restrict__ tl0,
                    const float* __restrict__ W1, __bf16* __restrict__ th1, __bf16* __restrict__ tl1,
                    const float* __restrict__ W2, __bf16* __restrict__ th2, __bf16* __restrict__ tl2,
                    const float* __restrict__ W3, __bf16* __restrict__ th3, __bf16* __restrict__ tl3)
{
    const float* W; __bf16* thi; __bf16* tlo;
    const int z = blockIdx.z;
    if (z == 0)      { W = W0; thi = th0; tlo = tl0; }
    else if (z == 1) { W = W1; thi = th1; tlo = tl1; }
    else if (z == 2) { W = W2; thi = th2; tlo = tl2; }
    else             { W = W3; thi = th3; tlo = tl3; }

    __shared__ float T[64][65];
    const int t = threadIdx.x;
    const int r0 = blockIdx.y * 64, c0 = blockIdx.x * 64;
#pragma unroll
    for (int it = 0; it < 4; ++it) {
        const int rl = (t >> 4) + it * 16;
        const int cl = (t & 15) * 4;
        float4 v = *(const float4*)&W[(size_t)(r0 + rl) * 1024 + c0 + cl];
        T[cl + 0][rl] = v.x; T[cl + 1][rl] = v.y;
        T[cl + 2][rl] = v.z; T[cl + 3][rl] = v.w;
    }
    __syncthreads();
    const int nl = t >> 2, ch = t & 3;
    float vals[16];
#pragma unroll
    for (int e = 0; e < 16; ++e) vals[e] = T[nl][ch * 16 + e];
    bf16x8 h0, h1, l0, l1;
#pragma unroll
    for (int e = 0; e < 8; ++e) {
        __bf16 hb = (__bf16)vals[e];
        h0[e] = hb; l0[e] = (__bf16)(vals[e] - (float)hb);
        __bf16 hb2 = (__bf16)vals[8 + e];
        h1[e] = hb2; l1[e] = (__bf16)(vals[8 + e] - (float)hb2);
    }
    const size_t base = (size_t)(c0 + nl) * 1024 + r0 + ch * 16;
    *(bf16x8*)&thi[base] = h0; *(bf16x8*)&thi[base + 8] = h1;
    *(bf16x8*)&tlo[base] = l0; *(bf16x8*)&tlo[base + 8] = l1;
}

// ---------------------------------------------------------------
// All-bf16 MFMA GEMM: 64x64 tile, BK=32, DMA-staged double-buffered
// LDS, hoisted per-lane source pointers, 1 barrier/K-step.
// ---------------------------------------------------------------
template<int MODE>
__global__ __launch_bounds__(256)
void gemm_bf16_kernel(const __bf16* __restrict__ Ahi, const __bf16* __restrict__ Alo,
                      const __bf16* __restrict__ Bhi, const __bf16* __restrict__ Blo,
                      const float* __restrict__ bias, float* __restrict__ out32,
                      __bf16* __restrict__ outHi, __bf16* __restrict__ outLo,
                      int M, int rows)
{
    __shared__ __align__(16) char LB[32768];   // As[2]@0/8192, Bs[2]@16384/24576

    const int t = threadIdx.x, w = t >> 6, l = t & 63;
    const int lr = l & 15, ls = l >> 4;
    const int m0 = blockIdx.y * 64, n0 = blockIdx.x * 64;

    f32x4 acc[4];
#pragma unroll
    for (int ct = 0; ct < 4; ++ct) acc[ct] = f32x4{0.f, 0.f, 0.f, 0.f};

    const int ar   = w * 16 + lr;
    const int a_hi = ar * 128 + (((2 * ls    ) ^ (ar & 7)) << 4);
    const int a_lo = ar * 128 + (((2 * ls + 1) ^ (ar & 7)) << 4);

    const __bf16* aA[2];
    const __bf16* bB[2];
#pragma unroll
    for (int i = 0; i < 2; ++i) {
        const int r = (w * 2 + i) * 8 + (l >> 3);
        const int un = (l & 7) ^ (r & 7);
        aA[i] = ((un & 1) ? Alo : Ahi) + (size_t)(m0 + r) * 1024 + (un >> 1) * 8;
        bB[i] = ((un & 1) ? Blo : Bhi) + (size_t)(n0 + r) * 1024 + (un >> 1) * 8;
    }

#define GSTAGE(k0_, buf_) {                                                       \
    _Pragma("unroll")                                                             \
    for (int i_ = 0; i_ < 2; ++i_) {                                              \
        GLD16(aA[i_] + (k0_), LB + (buf_) * 8192 + (w * 2 + i_) * 1024);          \
        GLD16(bB[i_] + (k0_), LB + 16384 + (buf_) * 8192 + (w * 2 + i_) * 1024);  \
    } }

    GSTAGE(0, 0);
    __syncthreads();

    for (int ks = 0; ks < 32; ++ks) {
        const int cur = ks & 1;
        if (ks < 31) GSTAGE((ks + 1) * 32, cur ^ 1);

        const char* As = LB + cur * 8192;
        const char* Bs = LB + 16384 + cur * 8192;
        const bf16x8 ah = *(const bf16x8*)(As + a_hi);
        const bf16x8 al = *(const bf16x8*)(As + a_lo);
        __builtin_amdgcn_s_setprio(1);
#pragma unroll
        for (int ct = 0; ct < 4; ++ct) {
            const int bc   = ct * 16 + lr;
            const int b_hi = bc * 128 + (((2 * ls    ) ^ (bc & 7)) << 4);
            const int b_lo = bc * 128 + (((2 * ls + 1) ^ (bc & 7)) << 4);
            const bf16x8 bh = *(const bf16x8*)(Bs + b_hi);
            const bf16x8 bl = *(const bf16x8*)(Bs + b_lo);
            acc[ct] = __builtin_amdgcn_mfma_f32_16x16x32_bf16(ah, bh, acc[ct], 0, 0, 0);
            acc[ct] = __builtin_amdgcn_mfma_f32_16x16x32_bf16(al, bh, acc[ct], 0, 0, 0);
            acc[ct] = __builtin_amdgcn_mfma_f32_16x16x32_bf16(ah, bl, acc[ct], 0, 0, 0);
        }
        __builtin_amdgcn_s_setprio(0);
        __syncthreads();
    }
#undef GSTAGE

    if (MODE == 2) {
        float* T = (float*)LB;   // [64][65]
#pragma unroll
        for (int ct = 0; ct < 4; ++ct) {
            const int nl = ct * 16 + lr;
            const float bv = bias[n0 + nl];
#pragma unroll
            for (int j = 0; j < 4; ++j)
                T[nl * 65 + w * 16 + ls * 4 + j] = acc[ct][j] + bv;
        }
        __syncthreads();
        const int dr = t >> 2, ch = t & 3;
        const int hh = n0 >> 6;
        const int mb = m0 + ch * 16;
        float vals[16];
#pragma unroll
        for (int e = 0; e < 16; ++e) vals[e] = T[dr * 65 + ch * 16 + e];
        const int bb0 = mb / rows;
        const int s0  = mb - bb0 * rows;
        if (mb + 15 < M && bb0 == (mb + 15) / rows && (s0 & 7) == 0) {
            bf16x8 h0, h1, l0, l1;
#pragma unroll
            for (int e = 0; e < 8; ++e) {
                __bf16 hb = (__bf16)vals[e];
                h0[e] = hb; l0[e] = (__bf16)(vals[e] - (float)hb);
                __bf16 hb2 = (__bf16)vals[8 + e];
                h1[e] = hb2; l1[e] = (__bf16)(vals[8 + e] - (float)hb2);
            }
            const size_t base = (((size_t)(bb0 * HN + hh) * DH + dr) << 10) + s0;
            *(bf16x8*)&outHi[base] = h0; *(bf16x8*)&outHi[base + 8] = h1;
            *(bf16x8*)&outLo[base] = l0; *(bf16x8*)&outLo[base + 8] = l1;
        } else {
#pragma unroll
            for (int e = 0; e < 16; ++e) {
                const int m = mb + e;
                if (m < M) {
                    const int bb = m / rows, s = m - bb * rows;
                    const size_t idx = (((size_t)(bb * HN + hh) * DH + dr) << 10) + s;
                    const __bf16 hb = (__bf16)vals[e];
                    outHi[idx] = hb;
                    outLo[idx] = (__bf16)(vals[e] - (float)hb);
                }
            }
        }
    } else {
#pragma unroll
        for (int ct = 0; ct < 4; ++ct) {
            const int n = n0 + ct * 16 + lr;
            const float bv = bias[n];
#pragma unroll
            for (int j = 0; j < 4; ++j) {
                const int m = m0 + w * 16 + ls * 4 + j;
                if (m >= M) continue;
                const float val = acc[ct][j] + bv;
                if (MODE == 1) {
                    out32[(size_t)m * DMODEL + n] = val;
                } else {
                    const int bb = m / rows, s = m - bb * rows;
                    const __bf16 hb = (__bf16)val;
                    const __bf16 lb = (__bf16)(val - (float)hb);
                    const size_t idx = (((size_t)(bb * HN + (n >> 6)) * SEQ + s) << 6) + (n & 63);
                    outHi[idx] = hb; outLo[idx] = lb;
                }
            }
        }
    }
}

// ---------------------------------------------------------------
// Pack mask -> bitmask [row][32 u32]. Wave per row.
// ---------------------------------------------------------------
__global__ __launch_bounds__(256)
void mask_pack_kernel(const int* __restrict__ mask, unsigned int* __restrict__ mb)
{
    const int row = blockIdx.x * 4 + (threadIdx.x >> 6);
    const int l   = threadIdx.x & 63;
    if (row >= 2 * SM1) return;
    const int* mrow = mask + (size_t)row * SM1;
    unsigned int* out = mb + (size_t)row * 32;
#pragma unroll
    for (int i = 0; i < 16; ++i) {
        const int c = i * 64 + l;
        const bool mv = (c < SM1) && (mrow[c] != 0);
        unsigned long long bal = __ballot(mv);
        if (l == 0) {
            out[i * 2]     = (unsigned int)bal;
            out[i * 2 + 1] = (unsigned int)(bal >> 32);
        }
    }
}

// ---------------------------------------------------------------
// Fused attention, 3 blocks/CU (LDS ~49.8KB): mask words loaded
// per-tile from L2 (no mbitsT), pass 1 double-buffers K across
// Kb+Vb, pass 2 single-K/single-V with 2-barrier schedule.
// ---------------------------------------------------------------
__global__ __launch_bounds__(512, 6)
void attn_fused_kernel(const __bf16* __restrict__ qhi, const __bf16* __restrict__ qlo,
                       const __bf16* __restrict__ khi, const __bf16* __restrict__ klo,
                       const __bf16* __restrict__ vthi, const __bf16* __restrict__ vtlo,
                       const unsigned int* __restrict__ mbG,
                       float* __restrict__ att,
                       __bf16* __restrict__ ctxHi, __bf16* __restrict__ ctxLo)
{
    __shared__ __align__(16) char QE[17408];   // Q 16KB / E[64][68] f32 / red[64][68]
    __shared__ __align__(16) char Kb[16384];   // K buffer (pass2) / K even tiles (pass1)
    __shared__ __align__(16) char Vb[16384];   // V buffer (pass2) / K odd tiles (pass1)
    __shared__ float invs[64];
    __shared__ float partial[64][2];

    const int id  = blockIdx.x;
    const int xcd = id & 7, slot = id >> 3;
    const int bh  = xcd + 8 * (slot >> 4);
    const int b   = bh >> 4, h = bh & 15;
    const int q0  = (slot & 15) * 64;

    const int t = threadIdx.x, w = t >> 6, l = t & 63;
    const int lr = l & 15, ls = l >> 4;
    const int g = w & 3, p = w >> 2;

    // ---- hoisted per-lane DMA source pointers ----
    const __bf16* kA[2];
    const __bf16* vA[2];
#pragma unroll
    for (int i = 0; i < 2; ++i) {
        const int seg = w * 2 + i;
        const int r  = seg * 4 + (l >> 4);
        const int cw = (l & 15) ^ (r & 15);
        kA[i] = ((cw >> 3) ? klo : khi) + ((size_t)bh * SEQ + r) * DH + (cw & 7) * 8;
        vA[i] = ((cw >> 3) ? vtlo : vthi) + (((size_t)bh * DH + r) << 10) + (cw & 7) * 8;
    }
    // mask row bases for this thread's 4 C-rows (clamped)
    const unsigned int* mrow4[4];
#pragma unroll
    for (int j = 0; j < 4; ++j) {
        int r = q0 + g * 16 + ls * 4 + j;
        if (r > SM1 - 1) r = SM1 - 1;
        mrow4[j] = mbG + ((size_t)b * SM1 + r) * 32 + p;
    }

#define KDMA(koff_, dst_) {                                                     \
    _Pragma("unroll")                                                           \
    for (int i_ = 0; i_ < 2; ++i_)                                              \
        GLD16(kA[i_] + (koff_), (dst_) + (w * 2 + i_) * 1024);                  \
    }
#define VDMA(coff_) {                                                           \
    _Pragma("unroll")                                                           \
    for (int i_ = 0; i_ < 2; ++i_)                                              \
        GLD16(vA[i_] + (coff_), Vb + (w * 2 + i_) * 1024);                      \
    }

    // ---- prologue: Q DMA + K(0)->Kb ----
#pragma unroll
    for (int i = 0; i < 2; ++i) {
        const int seg = w * 2 + i;
        const int r = seg * 4 + (l >> 4);
        const int cw = (l & 15) ^ (r & 15);
        int qrow = q0 + r + 1; if (qrow > 1023) qrow = 1023;
        const __bf16* src = ((cw >> 3) ? qlo : qhi)
            + ((size_t)bh * SEQ + qrow) * DH + (cw & 7) * 8;
        GLD16(src, QE + seg * 1024);
    }
    KDMA(0, Kb);
    __syncthreads();

    const int arow = g * 16 + lr;
    const bf16x8 a0h = *(const bf16x8*)(QE + arow * 256 + (((ls     ) ^ lr) << 4));
    const bf16x8 a1h = *(const bf16x8*)(QE + arow * 256 + ((( 4 + ls) ^ lr) << 4));
    const bf16x8 a0l = *(const bf16x8*)(QE + arow * 256 + ((( 8 + ls) ^ lr) << 4));
    const bf16x8 a1l = *(const bf16x8*)(QE + arow * 256 + (((12 + ls) ^ lr) << 4));
    __syncthreads();   // Q area free (becomes E in pass 2)

    // ================= pass 1: row sums of exp =================
    float rsum[4] = {0.f, 0.f, 0.f, 0.f};
    for (int kt = 0; kt < 16; ++kt) {
        const char* KB = (kt & 1) ? Vb : Kb;
        if (kt < 15) KDMA((kt + 1) * 4096, (kt & 1) ? Kb : Vb);

        unsigned int wm4[4];
#pragma unroll
        for (int j = 0; j < 4; ++j) wm4[j] = mrow4[j][kt * 2];

#pragma unroll
        for (int i = 0; i < 2; ++i) {
            const int ct = p * 2 + i;
            const int kr16 = ct * 16 + lr;
            const bf16x8 b0h = *(const bf16x8*)(KB + kr16 * 256 + (((ls     ) ^ lr) << 4));
            const bf16x8 b1h = *(const bf16x8*)(KB + kr16 * 256 + ((( 4 + ls) ^ lr) << 4));
            const bf16x8 b0l = *(const bf16x8*)(KB + kr16 * 256 + ((( 8 + ls) ^ lr) << 4));
            const bf16x8 b1l = *(const bf16x8*)(KB + kr16 * 256 + (((12 + ls) ^ lr) << 4));

            f32x4 acc = {0.f, 0.f, 0.f, 0.f};
            __builtin_amdgcn_s_setprio(1);
            acc = __builtin_amdgcn_mfma_f32_16x16x32_bf16(a0h, b0h, acc, 0, 0, 0);
            acc = __builtin_amdgcn_mfma_f32_16x16x32_bf16(a0l, b0h, acc, 0, 0, 0);
            acc = __builtin_amdgcn_mfma_f32_16x16x32_bf16(a0h, b0l, acc, 0, 0, 0);
            acc = __builtin_amdgcn_mfma_f32_16x16x32_bf16(a1h, b1h, acc, 0, 0, 0);
            acc = __builtin_amdgcn_mfma_f32_16x16x32_bf16(a1l, b1h, acc, 0, 0, 0);
            acc = __builtin_amdgcn_mfma_f32_16x16x32_bf16(a1h, b1l, acc, 0, 0, 0);
            __builtin_amdgcn_s_setprio(0);

            const int c = kt * 64 + ct * 16 + lr;
#pragma unroll
            for (int j = 0; j < 4; ++j) {
                const int r = q0 + g * 16 + ls * 4 + j;
                if (r < SM1 && c < SM1) {
                    float sc = fmaxf(acc[j] * 0.125f, 0.f);
                    if ((wm4[j] >> ((ct & 1) * 16 + lr)) & 1u) sc = -1e9f;
                    rsum[j] += __expf(sc);
                }
            }
        }
        __syncthreads();
    }

    KDMA(0, Kb);   // K(0) for pass 2 (drains under the reduce)
    VDMA(0);       // V(0) for pass 2

#pragma unroll
    for (int j = 0; j < 4; ++j) {
        rsum[j] += __shfl_xor(rsum[j], 1, 64);
        rsum[j] += __shfl_xor(rsum[j], 2, 64);
        rsum[j] += __shfl_xor(rsum[j], 4, 64);
        rsum[j] += __shfl_xor(rsum[j], 8, 64);
    }
    if (lr == 0) {
#pragma unroll
        for (int j = 0; j < 4; ++j)
            partial[g * 16 + ls * 4 + j][p] = rsum[j];
    }
    __syncthreads();
    if (t < 64) {
        const float s = partial[t][0] + partial[t][1];
        invs[t] = (q0 + t < SM1) ? 1.0f / s : 0.f;
    }
    __syncthreads();
    float inv4[4];
#pragma unroll
    for (int j = 0; j < 4; ++j) inv4[j] = invs[g * 16 + ls * 4 + j];

    // ================= pass 2: weights + PV =================
    float* E = (float*)QE;   // [64][68]
    f32x4 oacc[4];
#pragma unroll
    for (int ct = 0; ct < 4; ++ct) oacc[ct] = f32x4{0.f, 0.f, 0.f, 0.f};

    for (int kt = 0; kt < 16; ++kt) {
        const int c0 = kt * 64;

        unsigned int wm4[4];
#pragma unroll
        for (int j = 0; j < 4; ++j) wm4[j] = mrow4[j][kt * 2];

#pragma unroll
        for (int i = 0; i < 2; ++i) {
            const int ct = p * 2 + i;
            const int kr16 = ct * 16 + lr;
            const bf16x8 b0h = *(const bf16x8*)(Kb + kr16 * 256 + (((ls     ) ^ lr) << 4));
            const bf16x8 b1h = *(const bf16x8*)(Kb + kr16 * 256 + ((( 4 + ls) ^ lr) << 4));
            const bf16x8 b0l = *(const bf16x8*)(Kb + kr16 * 256 + ((( 8 + ls) ^ lr) << 4));
            const bf16x8 b1l = *(const bf16x8*)(Kb + kr16 * 256 + (((12 + ls) ^ lr) << 4));

            f32x4 acc = {0.f, 0.f, 0.f, 0.f};
            __builtin_amdgcn_s_setprio(1);
            acc = __builtin_amdgcn_mfma_f32_16x16x32_bf16(a0h, b0h, acc, 0, 0, 0);
            acc = __builtin_amdgcn_mfma_f32_16x16x32_bf16(a0l, b0h, acc, 0, 0, 0);
            acc = __builtin_amdgcn_mfma_f32_16x16x32_bf16(a0h, b0l, acc, 0, 0, 0);
            acc = __builtin_amdgcn_mfma_f32_16x16x32_bf16(a1h, b1h, acc, 0, 0, 0);
            acc = __builtin_amdgcn_mfma_f32_16x16x32_bf16(a1l, b1h, acc, 0, 0, 0);
            acc = __builtin_amdgcn_mfma_f32_16x16x32_bf16(a1h, b1l, acc, 0, 0, 0);
            __builtin_amdgcn_s_setprio(0);

            const int c = c0 + ct * 16 + lr;
#pragma unroll
            for (int j = 0; j < 4; ++j) {
                const int r = q0 + g * 16 + ls * 4 + j;
                float v = 0.f;
                if (r < SM1 && c < SM1) {
                    float sc = fmaxf(acc[j] * 0.125f, 0.f);
                    if ((wm4[j] >> ((ct & 1) * 16 + lr)) & 1u) sc = -1e9f;
                    v = __expf(sc) * inv4[j];
                }
                E[(g * 16 + ls * 4 + j) * 68 + ct * 16 + lr] = v;
            }
        }
        __syncthreads();   // B1: E ready; Kb consumed; VDMA(kt) drained

        if (kt < 15) KDMA((kt + 1) * 4096, Kb);

        // ---- coalesced weight write-out from E (64 rows x 64 cols) ----
#pragma unroll
        for (int it = 0; it < 2; ++it) {
            const int idw = t + it * 512;
            const int r = idw >> 4, q4 = idw & 15;
            const int rr = q0 + r, cc = c0 + q4 * 4;
            if (rr < SM1) {
                f32x4 vv = *(const f32x4*)&E[r * 68 + q4 * 4];
                float* dst = &att[((size_t)bh * SM1 + rr) * SM1 + cc];
                if (cc + 4 <= SM1) {
                    __builtin_nontemporal_store(vv, (f32x4*)dst);
                } else {
                    if (cc + 0 < SM1) dst[0] = vv.x;
                    if (cc + 1 < SM1) dst[1] = vv.y;
                    if (cc + 2 < SM1) dst[2] = vv.z;
                }
            }
        }

        // ---- PV: parity p handles keys p*32..p*32+31 of the tile ----
        {
            const int pr = g * 16 + lr;
            const f32x4 p0 = *(const f32x4*)&E[pr * 68 + p * 32 + ls * 8];
            const f32x4 p1 = *(const f32x4*)&E[pr * 68 + p * 32 + ls * 8 + 4];
            float pf[8] = {p0.x, p0.y, p0.z, p0.w, p1.x, p1.y, p1.z, p1.w};
            bf16x8 ph, pl;
#pragma unroll
            for (int e = 0; e < 8; ++e) {
                const __bf16 hb = (__bf16)pf[e];
                ph[e] = hb;
                pl[e] = (__bf16)(pf[e] - (float)hb);
            }
#pragma unroll
            for (int ct = 0; ct < 4; ++ct) {
                const int vr16 = ct * 16 + lr;
                const bf16x8 vh = *(const bf16x8*)(Vb + vr16 * 256 + (((p * 4 + ls    ) ^ lr) << 4));
                const bf16x8 vl = *(const bf16x8*)(Vb + vr16 * 256 + (((8 + p * 4 + ls) ^ lr) << 4));
                __builtin_amdgcn_s_setprio(1);
                oacc[ct] = __builtin_amdgcn_mfma_f32_16x16x32_bf16(ph, vh, oacc[ct], 0, 0, 0);
                oacc[ct] = __builtin_amdgcn_mfma_f32_16x16x32_bf16(pl, vh, oacc[ct], 0, 0, 0);
                oacc[ct] = __builtin_amdgcn_mfma_f32_16x16x32_bf16(ph, vl, oacc[ct], 0, 0, 0);
                __builtin_amdgcn_s_setprio(0);
            }
        }
        __syncthreads();   // B2: PV done (Vb free); KDMA drained

        if (kt < 15) VDMA((kt + 1) * 64);
    }

    // ---- cross-parity reduce and ctx hi/lo plane write ----
    float* red = (float*)QE;   // [64][68]
    if (p == 1) {
#pragma unroll
        for (int ct = 0; ct < 4; ++ct)
#pragma unroll
            for (int j = 0; j < 4; ++j)
                red[(g * 16 + ls * 4 + j) * 68 + ct * 16 + lr] = oacc[ct][j];
    }
    __syncthreads();
    if (p == 0) {
#pragma unroll
        for (int ct = 0; ct < 4; ++ct)
#pragma unroll
            for (int j = 0; j < 4; ++j) {
                const int r = q0 + g * 16 + ls * 4 + j;
                if (r < SM1) {
                    const float val =
                        oacc[ct][j] + red[(g * 16 + ls * 4 + j) * 68 + ct * 16 + lr];
                    const size_t idx =
                        ((size_t)b * SM1 + r) * DMODEL + h * DH + ct * 16 + lr;
                    const __bf16 hb = (__bf16)val;
                    ctxHi[idx] = hb;
                    ctxLo[idx] = (__bf16)(val - (float)hb);
                }
            }
    }
#undef KDMA
#undef VDMA
}

// ---------------------------------------------------------------
extern "C" void kernel_launch(void* const* d_in, const int* in_sizes, int n_in,
                              void* d_out, int out_size, void* d_ws, size_t ws_size,
                              hipStream_t stream) {
    const float* q    = (const float*)d_in[0];
    const float* k    = (const float*)d_in[1];
    const float* v    = (const float*)d_in[2];
    const int*   mask = (const int*)  d_in[4];
    const float* Wq   = (const float*)d_in[5];
    const float* bq   = (const float*)d_in[6];
    const float* Wk   = (const float*)d_in[7];
    const float* bk   = (const float*)d_in[8];
    const float* Wv   = (const float*)d_in[9];
    const float* bv   = (const float*)d_in[10];
    const float* Wo   = (const float*)d_in[11];
    const float* bo   = (const float*)d_in[12];

    float* out0 = (float*)d_out;                       // [2,1023,1024]
    float* att  = out0 + (size_t)2 * SM1 * DMODEL;     // [2,16,1023,1023]

    const size_t NX  = (size_t)2048 * 1024;
    const size_t NW  = (size_t)1024 * 1024;
    const size_t NQH = (size_t)2 * HN * SEQ * DH;
    const size_t NVT = (size_t)2 * HN * DH * 1024;

    __bf16* p2  = (__bf16*)d_ws;
    __bf16* qSh = p2; p2 += NX;  __bf16* qSl = p2; p2 += NX;
    __bf16* kSh = p2; p2 += NX;  __bf16* kSl = p2; p2 += NX;
    __bf16* vSh = p2; p2 += NX;  __bf16* vSl = p2; p2 += NX;
    __bf16* WqTh = p2; p2 += NW; __bf16* WqTl = p2; p2 += NW;
    __bf16* WkTh = p2; p2 += NW; __bf16* WkTl = p2; p2 += NW;
    __bf16* WvTh = p2; p2 += NW; __bf16* WvTl = p2; p2 += NW;
    __bf16* WoTh = p2; p2 += NW; __bf16* WoTl = p2; p2 += NW;
    __bf16* qhh = p2; p2 += NQH; __bf16* qhl = p2; p2 += NQH;
    __bf16* khh = p2; p2 += NQH; __bf16* khl = p2; p2 += NQH;
    __bf16* vth = p2; p2 += NVT; __bf16* vtl = p2; p2 += NVT;
    unsigned int* mbG = (unsigned int*)p2;             // [2046][32]
    __bf16* ctxHi = qSh;
    __bf16* ctxLo = qSl;

    (void)hipMemsetAsync(vth, 0, 2 * NVT * sizeof(__bf16), stream);

    mask_pack_kernel<<<dim3(512), 256, 0, stream>>>(mask, mbG);

    split3_kernel<<<dim3(512, 3), 256, 0, stream>>>(
        q, qSh, qSl, 2048 * 1024 / 8,
        k, kSh, kSl, 2048 * 1024 / 8,
        v, vSh, vSl, 2046 * 1024 / 8);

    splitT4_kernel<<<dim3(16, 16, 4), 256, 0, stream>>>(
        Wq, WqTh, WqTl, Wk, WkTh, WkTl, Wv, WvTh, WvTl, Wo, WoTh, WoTl);

    gemm_bf16_kernel<0><<<dim3(16, 32), 256, 0, stream>>>(qSh, qSl, WqTh, WqTl, bq,
                                                          nullptr, qhh, qhl, 2 * SEQ, SEQ);
    gemm_bf16_kernel<0><<<dim3(16, 32), 256, 0, stream>>>(kSh, kSl, WkTh, WkTl, bk,
                                                          nullptr, khh, khl, 2 * SEQ, SEQ);
    gemm_bf16_kernel<2><<<dim3(16, 32), 256, 0, stream>>>(vSh, vSl, WvTh, WvTl, bv,
                                                          nullptr, vth, vtl, 2 * SM1, SM1);

    attn_fused_kernel<<<dim3(512), 512, 0, stream>>>(qhh, qhl, khh, khl, vth, vtl,
                                                     mbG, att, ctxHi, ctxLo);

    gemm_bf16_kernel<1><<<dim3(16, 32), 256, 0, stream>>>(ctxHi, ctxLo, WoTh, WoTl, bo,
                                                          out0, nullptr, nullptr, 2 * SM1, SM1);
}

// Round 20
// 227.564 us; speedup vs baseline: 1.4224x; 1.4224x over previous
//
#include <hip/hip_runtime.h>
#include <math.h>

#define HN 16
#define SEQ 1024
#define DMODEL 1024
#define DH 64
#define SM1 1023   // S-1

typedef float  f32x4  __attribute__((ext_vector_type(4)));
typedef __bf16 bf16x8 __attribute__((ext_vector_type(8)));

// async global->LDS DMA, 16B per lane, dest = wave-uniform base + lane*16
#define GLD16(gsrc, ldst) \
    __builtin_amdgcn_global_load_lds((const __attribute__((address_space(1))) void*)(gsrc), \
                                     (__attribute__((address_space(3))) void*)(ldst), 16, 0, 0)

// ---------------------------------------------------------------
// split3: fp32 -> bf16 hi/lo planes for q,k,v in one launch.
// ---------------------------------------------------------------
__global__ __launch_bounds__(256)
void split3_kernel(const float* __restrict__ s0, __bf16* __restrict__ h0, __bf16* __restrict__ l0, int n0,
                   const float* __restrict__ s1, __bf16* __restrict__ h1, __bf16* __restrict__ l1, int n1,
                   const float* __restrict__ s2, __bf16* __restrict__ h2, __bf16* __restrict__ l2, int n2)
{
    const float* src; __bf16* hi; __bf16* lo; int nchunks;
    if (blockIdx.y == 0)      { src = s0; hi = h0; lo = l0; nchunks = n0; }
    else if (blockIdx.y == 1) { src = s1; hi = h1; lo = l1; nchunks = n1; }
    else                      { src = s2; hi = h2; lo = l2; nchunks = n2; }

    for (int i = blockIdx.x * 256 + threadIdx.x; i < nchunks; i += gridDim.x * 256) {
        float4 v0 = *(const float4*)&src[(size_t)i * 8];
        float4 v1 = *(const float4*)&src[(size_t)i * 8 + 4];
        float xa[8] = {v0.x, v0.y, v0.z, v0.w, v1.x, v1.y, v1.z, v1.w};
        bf16x8 h8, l8;
#pragma unroll
        for (int e = 0; e < 8; ++e) {
            __bf16 hb = (__bf16)xa[e];
            h8[e] = hb;
            l8[e] = (__bf16)(xa[e] - (float)hb);
        }
        *(bf16x8*)&hi[(size_t)i * 8] = h8;
        *(bf16x8*)&lo[(size_t)i * 8] = l8;
    }
}

// ---------------------------------------------------------------
// splitT4: W[1024][1024] fp32 -> transposed hi/lo planes, 4 weights.
// ---------------------------------------------------------------
__global__ __launch_bounds__(256)
void splitT4_kernel(const float* __restrict__ W0, __bf16* __restrict__ th0, __bf16* __restrict__ tl0,
                    const float* __restrict__ W1, __bf16* __restrict__ th1, __bf16* __restrict__ tl1,
                    const float* __restrict__ W2, __bf16* __restrict__ th2, __bf16* __restrict__ tl2,
                    const float* __restrict__ W3, __bf16* __restrict__ th3, __bf16* __restrict__ tl3)
{
    const float* W; __bf16* thi; __bf16* tlo;
    const int z = blockIdx.z;
    if (z == 0)      { W = W0; thi = th0; tlo = tl0; }
    else if (z == 1) { W = W1; thi = th1; tlo = tl1; }
    else if (z == 2) { W = W2; thi = th2; tlo = tl2; }
    else             { W = W3; thi = th3; tlo = tl3; }

    __shared__ float T[64][65];
    const int t = threadIdx.x;
    const int r0 = blockIdx.y * 64, c0 = blockIdx.x * 64;
#pragma unroll
    for (int it = 0; it < 4; ++it) {
        const int rl = (t >> 4) + it * 16;
        const int cl = (t & 15) * 4;
        float4 v = *(const float4*)&W[(size_t)(r0 + rl) * 1024 + c0 + cl];
        T[cl + 0][rl] = v.x; T[cl + 1][rl] = v.y;
        T[cl + 2][rl] = v.z; T[cl + 3][rl] = v.w;
    }
    __syncthreads();
    const int nl = t >> 2, ch = t & 3;
    float vals[16];
#pragma unroll
    for (int e = 0; e < 16; ++e) vals[e] = T[nl][ch * 16 + e];
    bf16x8 h0, h1, l0, l1;
#pragma unroll
    for (int e = 0; e < 8; ++e) {
        __bf16 hb = (__bf16)vals[e];
        h0[e] = hb; l0[e] = (__bf16)(vals[e] - (float)hb);
        __bf16 hb2 = (__bf16)vals[8 + e];
        h1[e] = hb2; l1[e] = (__bf16)(vals[8 + e] - (float)hb2);
    }
    const size_t base = (size_t)(c0 + nl) * 1024 + r0 + ch * 16;
    *(bf16x8*)&thi[base] = h0; *(bf16x8*)&thi[base + 8] = h1;
    *(bf16x8*)&tlo[base] = l0; *(bf16x8*)&tlo[base + 8] = l1;
}

// ---------------------------------------------------------------
// All-bf16 MFMA GEMM: 64x64 tile, BK=32, DMA-staged double-buffered
// LDS, hoisted per-lane source pointers, 1 barrier/K-step.
// ---------------------------------------------------------------
template<int MODE>
__global__ __launch_bounds__(256)
void gemm_bf16_kernel(const __bf16* __restrict__ Ahi, const __bf16* __restrict__ Alo,
                      const __bf16* __restrict__ Bhi, const __bf16* __restrict__ Blo,
                      const float* __restrict__ bias, float* __restrict__ out32,
                      __bf16* __restrict__ outHi, __bf16* __restrict__ outLo,
                      int M, int rows)
{
    __shared__ __align__(16) char LB[32768];   // As[2]@0/8192, Bs[2]@16384/24576

    const int t = threadIdx.x, w = t >> 6, l = t & 63;
    const int lr = l & 15, ls = l >> 4;
    const int m0 = blockIdx.y * 64, n0 = blockIdx.x * 64;

    f32x4 acc[4];
#pragma unroll
    for (int ct = 0; ct < 4; ++ct) acc[ct] = f32x4{0.f, 0.f, 0.f, 0.f};

    const int ar   = w * 16 + lr;
    const int a_hi = ar * 128 + (((2 * ls    ) ^ (ar & 7)) << 4);
    const int a_lo = ar * 128 + (((2 * ls + 1) ^ (ar & 7)) << 4);

    const __bf16* aA[2];
    const __bf16* bB[2];
#pragma unroll
    for (int i = 0; i < 2; ++i) {
        const int r = (w * 2 + i) * 8 + (l >> 3);
        const int un = (l & 7) ^ (r & 7);
        aA[i] = ((un & 1) ? Alo : Ahi) + (size_t)(m0 + r) * 1024 + (un >> 1) * 8;
        bB[i] = ((un & 1) ? Blo : Bhi) + (size_t)(n0 + r) * 1024 + (un >> 1) * 8;
    }

#define GSTAGE(k0_, buf_) {                                                       \
    _Pragma("unroll")                                                             \
    for (int i_ = 0; i_ < 2; ++i_) {                                              \
        GLD16(aA[i_] + (k0_), LB + (buf_) * 8192 + (w * 2 + i_) * 1024);          \
        GLD16(bB[i_] + (k0_), LB + 16384 + (buf_) * 8192 + (w * 2 + i_) * 1024);  \
    } }

    GSTAGE(0, 0);
    __syncthreads();

    for (int ks = 0; ks < 32; ++ks) {
        const int cur = ks & 1;
        if (ks < 31) GSTAGE((ks + 1) * 32, cur ^ 1);

        const char* As = LB + cur * 8192;
        const char* Bs = LB + 16384 + cur * 8192;
        const bf16x8 ah = *(const bf16x8*)(As + a_hi);
        const bf16x8 al = *(const bf16x8*)(As + a_lo);
        __builtin_amdgcn_s_setprio(1);
#pragma unroll
        for (int ct = 0; ct < 4; ++ct) {
            const int bc   = ct * 16 + lr;
            const int b_hi = bc * 128 + (((2 * ls    ) ^ (bc & 7)) << 4);
            const int b_lo = bc * 128 + (((2 * ls + 1) ^ (bc & 7)) << 4);
            const bf16x8 bh = *(const bf16x8*)(Bs + b_hi);
            const bf16x8 bl = *(const bf16x8*)(Bs + b_lo);
            acc[ct] = __builtin_amdgcn_mfma_f32_16x16x32_bf16(ah, bh, acc[ct], 0, 0, 0);
            acc[ct] = __builtin_amdgcn_mfma_f32_16x16x32_bf16(al, bh, acc[ct], 0, 0, 0);
            acc[ct] = __builtin_amdgcn_mfma_f32_16x16x32_bf16(ah, bl, acc[ct], 0, 0, 0);
        }
        __builtin_amdgcn_s_setprio(0);
        __syncthreads();
    }
#undef GSTAGE

    if (MODE == 2) {
        float* T = (float*)LB;   // [64][65]
#pragma unroll
        for (int ct = 0; ct < 4; ++ct) {
            const int nl = ct * 16 + lr;
            const float bv = bias[n0 + nl];
#pragma unroll
            for (int j = 0; j < 4; ++j)
                T[nl * 65 + w * 16 + ls * 4 + j] = acc[ct][j] + bv;
        }
        __syncthreads();
        const int dr = t >> 2, ch = t & 3;
        const int hh = n0 >> 6;
        const int mb = m0 + ch * 16;
        float vals[16];
#pragma unroll
        for (int e = 0; e < 16; ++e) vals[e] = T[dr * 65 + ch * 16 + e];
        const int bb0 = mb / rows;
        const int s0  = mb - bb0 * rows;
        if (mb + 15 < M && bb0 == (mb + 15) / rows && (s0 & 7) == 0) {
            bf16x8 h0, h1, l0, l1;
#pragma unroll
            for (int e = 0; e < 8; ++e) {
                __bf16 hb = (__bf16)vals[e];
                h0[e] = hb; l0[e] = (__bf16)(vals[e] - (float)hb);
                __bf16 hb2 = (__bf16)vals[8 + e];
                h1[e] = hb2; l1[e] = (__bf16)(vals[8 + e] - (float)hb2);
            }
            const size_t base = (((size_t)(bb0 * HN + hh) * DH + dr) << 10) + s0;
            *(bf16x8*)&outHi[base] = h0; *(bf16x8*)&outHi[base + 8] = h1;
            *(bf16x8*)&outLo[base] = l0; *(bf16x8*)&outLo[base + 8] = l1;
        } else {
#pragma unroll
            for (int e = 0; e < 16; ++e) {
                const int m = mb + e;
                if (m < M) {
                    const int bb = m / rows, s = m - bb * rows;
                    const size_t idx = (((size_t)(bb * HN + hh) * DH + dr) << 10) + s;
                    const __bf16 hb = (__bf16)vals[e];
                    outHi[idx] = hb;
                    outLo[idx] = (__bf16)(vals[e] - (float)hb);
                }
            }
        }
    } else {
#pragma unroll
        for (int ct = 0; ct < 4; ++ct) {
            const int n = n0 + ct * 16 + lr;
            const float bv = bias[n];
#pragma unroll
            for (int j = 0; j < 4; ++j) {
                const int m = m0 + w * 16 + ls * 4 + j;
                if (m >= M) continue;
                const float val = acc[ct][j] + bv;
                if (MODE == 1) {
                    out32[(size_t)m * DMODEL + n] = val;
                } else {
                    const int bb = m / rows, s = m - bb * rows;
                    const __bf16 hb = (__bf16)val;
                    const __bf16 lb = (__bf16)(val - (float)hb);
                    const size_t idx = (((size_t)(bb * HN + (n >> 6)) * SEQ + s) << 6) + (n & 63);
                    outHi[idx] = hb; outLo[idx] = lb;
                }
            }
        }
    }
}

// ---------------------------------------------------------------
// Pack mask -> bitmask [row][32 u32]. Wave per row.
// ---------------------------------------------------------------
__global__ __launch_bounds__(256)
void mask_pack_kernel(const int* __restrict__ mask, unsigned int* __restrict__ mb)
{
    const int row = blockIdx.x * 4 + (threadIdx.x >> 6);
    const int l   = threadIdx.x & 63;
    if (row >= 2 * SM1) return;
    const int* mrow = mask + (size_t)row * SM1;
    unsigned int* out = mb + (size_t)row * 32;
#pragma unroll
    for (int i = 0; i < 16; ++i) {
        const int c = i * 64 + l;
        const bool mv = (c < SM1) && (mrow[c] != 0);
        unsigned long long bal = __ballot(mv);
        if (l == 0) {
            out[i * 2]     = (unsigned int)bal;
            out[i * 2 + 1] = (unsigned int)(bal >> 32);
        }
    }
}

// ---------------------------------------------------------------
// Fused attention (R16 structure + hoisted DMA pointers only).
// ---------------------------------------------------------------
__global__ __launch_bounds__(512, 4)
void attn_fused_kernel(const __bf16* __restrict__ qhi, const __bf16* __restrict__ qlo,
                       const __bf16* __restrict__ khi, const __bf16* __restrict__ klo,
                       const __bf16* __restrict__ vthi, const __bf16* __restrict__ vtlo,
                       const unsigned int* __restrict__ mbG,
                       float* __restrict__ att,
                       __bf16* __restrict__ ctxHi, __bf16* __restrict__ ctxLo)
{
    __shared__ __align__(16) char QE[17408];        // Q 16KB / E[64][68] f32 / red[64][68]
    __shared__ __align__(16) char Kb[2][16384];
    __shared__ __align__(16) char Vb[16384];
    __shared__ unsigned int mbitsT[32][64];
    __shared__ float invs[64];
    __shared__ float partial[64][2];

    const int id  = blockIdx.x;
    const int xcd = id & 7, slot = id >> 3;
    const int bh  = xcd + 8 * (slot >> 4);
    const int b   = bh >> 4, h = bh & 15;
    const int q0  = (slot & 15) * 64;

    const int t = threadIdx.x, w = t >> 6, l = t & 63;
    const int lr = l & 15, ls = l >> 4;
    const int g = w & 3, p = w >> 2;

    // ---- hoisted per-lane DMA source pointers ----
    const __bf16* kA[2];
    const __bf16* vA[2];
#pragma unroll
    for (int i = 0; i < 2; ++i) {
        const int seg = w * 2 + i;
        const int r  = seg * 4 + (l >> 4);
        const int cw = (l & 15) ^ (r & 15);
        kA[i] = ((cw >> 3) ? klo : khi) + ((size_t)bh * SEQ + r) * DH + (cw & 7) * 8;
        vA[i] = ((cw >> 3) ? vtlo : vthi) + (((size_t)bh * DH + r) << 10) + (cw & 7) * 8;
    }

#define KDMA(koff_, b_) {                                                       \
    _Pragma("unroll")                                                           \
    for (int i_ = 0; i_ < 2; ++i_)                                              \
        GLD16(kA[i_] + (koff_), Kb[b_] + (w * 2 + i_) * 1024);                  \
    }
#define VDMA(coff_) {                                                           \
    _Pragma("unroll")                                                           \
    for (int i_ = 0; i_ < 2; ++i_)                                              \
        GLD16(vA[i_] + (coff_), Vb + (w * 2 + i_) * 1024);                      \
    }

    // ---- prologue: Q DMA + K(0) DMA + mask bits ----
#pragma unroll
    for (int i = 0; i < 2; ++i) {
        const int seg = w * 2 + i;
        const int r = seg * 4 + (l >> 4);
        const int cw = (l & 15) ^ (r & 15);
        int qrow = q0 + r + 1; if (qrow > 1023) qrow = 1023;
        const __bf16* src = ((cw >> 3) ? qlo : qhi)
            + ((size_t)bh * SEQ + qrow) * DH + (cw & 7) * 8;
        GLD16(src, QE + seg * 1024);
    }
    KDMA(0, 0);
#pragma unroll
    for (int it = 0; it < 4; ++it) {
        const int idm = t + it * 512;
        const int cw = idm & 31, r = idm >> 5;
        const int rr = q0 + r;
        mbitsT[cw][r] = (rr < SM1) ? mbG[((size_t)b * SM1 + rr) * 32 + cw] : 0u;
    }
    __syncthreads();

    const int arow = g * 16 + lr;
    const bf16x8 a0h = *(const bf16x8*)(QE + arow * 256 + (((ls     ) ^ lr) << 4));
    const bf16x8 a1h = *(const bf16x8*)(QE + arow * 256 + ((( 4 + ls) ^ lr) << 4));
    const bf16x8 a0l = *(const bf16x8*)(QE + arow * 256 + ((( 8 + ls) ^ lr) << 4));
    const bf16x8 a1l = *(const bf16x8*)(QE + arow * 256 + (((12 + ls) ^ lr) << 4));
    __syncthreads();   // Q area free (becomes E in pass 2)

    // ================= pass 1: row sums of exp =================
    float rsum[4] = {0.f, 0.f, 0.f, 0.f};
    for (int kt = 0; kt < 16; ++kt) {
        const char* KB = Kb[kt & 1];
        if (kt < 15) KDMA((kt + 1) * 4096, (kt + 1) & 1);

#pragma unroll
        for (int i = 0; i < 2; ++i) {
            const int ct = p * 2 + i;
            const int kr16 = ct * 16 + lr;
            const bf16x8 b0h = *(const bf16x8*)(KB + kr16 * 256 + (((ls     ) ^ lr) << 4));
            const bf16x8 b1h = *(const bf16x8*)(KB + kr16 * 256 + ((( 4 + ls) ^ lr) << 4));
            const bf16x8 b0l = *(const bf16x8*)(KB + kr16 * 256 + ((( 8 + ls) ^ lr) << 4));
            const bf16x8 b1l = *(const bf16x8*)(KB + kr16 * 256 + (((12 + ls) ^ lr) << 4));

            f32x4 acc = {0.f, 0.f, 0.f, 0.f};
            __builtin_amdgcn_s_setprio(1);
            acc = __builtin_amdgcn_mfma_f32_16x16x32_bf16(a0h, b0h, acc, 0, 0, 0);
            acc = __builtin_amdgcn_mfma_f32_16x16x32_bf16(a0l, b0h, acc, 0, 0, 0);
            acc = __builtin_amdgcn_mfma_f32_16x16x32_bf16(a0h, b0l, acc, 0, 0, 0);
            acc = __builtin_amdgcn_mfma_f32_16x16x32_bf16(a1h, b1h, acc, 0, 0, 0);
            acc = __builtin_amdgcn_mfma_f32_16x16x32_bf16(a1l, b1h, acc, 0, 0, 0);
            acc = __builtin_amdgcn_mfma_f32_16x16x32_bf16(a1h, b1l, acc, 0, 0, 0);
            __builtin_amdgcn_s_setprio(0);

            const int c = kt * 64 + ct * 16 + lr;
            const int wmi = kt * 2 + (ct >> 1);
#pragma unroll
            for (int j = 0; j < 4; ++j) {
                const int r = q0 + g * 16 + ls * 4 + j;
                if (r < SM1 && c < SM1) {
                    float sc = fmaxf(acc[j] * 0.125f, 0.f);
                    const unsigned int wm = mbitsT[wmi][g * 16 + ls * 4 + j];
                    if ((wm >> ((ct & 1) * 16 + lr)) & 1u) sc = -1e9f;
                    rsum[j] += __expf(sc);
                }
            }
        }
        __syncthreads();
    }

    KDMA(0, 0);   // K(0) for pass 2 (drains under the reduce)

#pragma unroll
    for (int j = 0; j < 4; ++j) {
        rsum[j] += __shfl_xor(rsum[j], 1, 64);
        rsum[j] += __shfl_xor(rsum[j], 2, 64);
        rsum[j] += __shfl_xor(rsum[j], 4, 64);
        rsum[j] += __shfl_xor(rsum[j], 8, 64);
    }
    if (lr == 0) {
#pragma unroll
        for (int j = 0; j < 4; ++j)
            partial[g * 16 + ls * 4 + j][p] = rsum[j];
    }
    __syncthreads();
    if (t < 64) {
        const float s = partial[t][0] + partial[t][1];
        invs[t] = (q0 + t < SM1) ? 1.0f / s : 0.f;
    }
    __syncthreads();
    float inv4[4];
#pragma unroll
    for (int j = 0; j < 4; ++j) inv4[j] = invs[g * 16 + ls * 4 + j];

    // ================= pass 2: weights + PV =================
    float* E = (float*)QE;   // [64][68]
    f32x4 oacc[4];
#pragma unroll
    for (int ct = 0; ct < 4; ++ct) oacc[ct] = f32x4{0.f, 0.f, 0.f, 0.f};

    for (int kt = 0; kt < 16; ++kt) {
        const int c0 = kt * 64;
        const char* KB = Kb[kt & 1];
        VDMA(c0);
        if (kt < 15) KDMA((kt + 1) * 4096, (kt + 1) & 1);

#pragma unroll
        for (int i = 0; i < 2; ++i) {
            const int ct = p * 2 + i;
            const int kr16 = ct * 16 + lr;
            const bf16x8 b0h = *(const bf16x8*)(KB + kr16 * 256 + (((ls     ) ^ lr) << 4));
            const bf16x8 b1h = *(const bf16x8*)(KB + kr16 * 256 + ((( 4 + ls) ^ lr) << 4));
            const bf16x8 b0l = *(const bf16x8*)(KB + kr16 * 256 + ((( 8 + ls) ^ lr) << 4));
            const bf16x8 b1l = *(const bf16x8*)(KB + kr16 * 256 + (((12 + ls) ^ lr) << 4));

            f32x4 acc = {0.f, 0.f, 0.f, 0.f};
            __builtin_amdgcn_s_setprio(1);
            acc = __builtin_amdgcn_mfma_f32_16x16x32_bf16(a0h, b0h, acc, 0, 0, 0);
            acc = __builtin_amdgcn_mfma_f32_16x16x32_bf16(a0l, b0h, acc, 0, 0, 0);
            acc = __builtin_amdgcn_mfma_f32_16x16x32_bf16(a0h, b0l, acc, 0, 0, 0);
            acc = __builtin_amdgcn_mfma_f32_16x16x32_bf16(a1h, b1h, acc, 0, 0, 0);
            acc = __builtin_amdgcn_mfma_f32_16x16x32_bf16(a1l, b1h, acc, 0, 0, 0);
            acc = __builtin_amdgcn_mfma_f32_16x16x32_bf16(a1h, b1l, acc, 0, 0, 0);
            __builtin_amdgcn_s_setprio(0);

            const int c = c0 + ct * 16 + lr;
            const int wmi = kt * 2 + (ct >> 1);
#pragma unroll
            for (int j = 0; j < 4; ++j) {
                const int r = q0 + g * 16 + ls * 4 + j;
                float v = 0.f;
                if (r < SM1 && c < SM1) {
                    float sc = fmaxf(acc[j] * 0.125f, 0.f);
                    const unsigned int wm = mbitsT[wmi][g * 16 + ls * 4 + j];
                    if ((wm >> ((ct & 1) * 16 + lr)) & 1u) sc = -1e9f;
                    v = __expf(sc) * inv4[j];
                }
                E[(g * 16 + ls * 4 + j) * 68 + ct * 16 + lr] = v;
            }
        }
        __syncthreads();   // B: E complete; V (and next K) drained

        // ---- coalesced weight write-out from E (64 rows x 64 cols) ----
#pragma unroll
        for (int it = 0; it < 2; ++it) {
            const int idw = t + it * 512;
            const int r = idw >> 4, q4 = idw & 15;
            const int rr = q0 + r, cc = c0 + q4 * 4;
            if (rr < SM1) {
                f32x4 vv = *(const f32x4*)&E[r * 68 + q4 * 4];
                float* dst = &att[((size_t)bh * SM1 + rr) * SM1 + cc];
                if (cc + 4 <= SM1) {
                    __builtin_nontemporal_store(vv, (f32x4*)dst);
                } else {
                    if (cc + 0 < SM1) dst[0] = vv.x;
                    if (cc + 1 < SM1) dst[1] = vv.y;
                    if (cc + 2 < SM1) dst[2] = vv.z;
                }
            }
        }

        // ---- PV: parity p handles keys p*32..p*32+31 of the tile ----
        {
            const int pr = g * 16 + lr;
            const f32x4 p0 = *(const f32x4*)&E[pr * 68 + p * 32 + ls * 8];
            const f32x4 p1 = *(const f32x4*)&E[pr * 68 + p * 32 + ls * 8 + 4];
            float pf[8] = {p0.x, p0.y, p0.z, p0.w, p1.x, p1.y, p1.z, p1.w};
            bf16x8 ph, pl;
#pragma unroll
            for (int e = 0; e < 8; ++e) {
                const __bf16 hb = (__bf16)pf[e];
                ph[e] = hb;
                pl[e] = (__bf16)(pf[e] - (float)hb);
            }
#pragma unroll
            for (int ct = 0; ct < 4; ++ct) {
                const int vr16 = ct * 16 + lr;
                const bf16x8 vh = *(const bf16x8*)(Vb + vr16 * 256 + (((p * 4 + ls    ) ^ lr) << 4));
                const bf16x8 vl = *(const bf16x8*)(Vb + vr16 * 256 + (((8 + p * 4 + ls) ^ lr) << 4));
                __builtin_amdgcn_s_setprio(1);
                oacc[ct] = __builtin_amdgcn_mfma_f32_16x16x32_bf16(ph, vh, oacc[ct], 0, 0, 0);
                oacc[ct] = __builtin_amdgcn_mfma_f32_16x16x32_bf16(pl, vh, oacc[ct], 0, 0, 0);
                oacc[ct] = __builtin_amdgcn_mfma_f32_16x16x32_bf16(ph, vl, oacc[ct], 0, 0, 0);
                __builtin_amdgcn_s_setprio(0);
            }
        }
        __syncthreads();   // C: PV done -> Vb free, E free
    }

    // ---- cross-parity reduce and ctx hi/lo plane write ----
    float* red = (float*)QE;   // [64][68]
    if (p == 1) {
#pragma unroll
        for (int ct = 0; ct < 4; ++ct)
#pragma unroll
            for (int j = 0; j < 4; ++j)
                red[(g * 16 + ls * 4 + j) * 68 + ct * 16 + lr] = oacc[ct][j];
    }
    __syncthreads();
    if (p == 0) {
#pragma unroll
        for (int ct = 0; ct < 4; ++ct)
#pragma unroll
            for (int j = 0; j < 4; ++j) {
                const int r = q0 + g * 16 + ls * 4 + j;
                if (r < SM1) {
                    const float val =
                        oacc[ct][j] + red[(g * 16 + ls * 4 + j) * 68 + ct * 16 + lr];
                    const size_t idx =
                        ((size_t)b * SM1 + r) * DMODEL + h * DH + ct * 16 + lr;
                    const __bf16 hb = (__bf16)val;
                    ctxHi[idx] = hb;
                    ctxLo[idx] = (__bf16)(val - (float)hb);
                }
            }
    }
#undef KDMA
#undef VDMA
}

// ---------------------------------------------------------------
extern "C" void kernel_launch(void* const* d_in, const int* in_sizes, int n_in,
                              void* d_out, int out_size, void* d_ws, size_t ws_size,
                              hipStream_t stream) {
    const float* q    = (const float*)d_in[0];
    const float* k    = (const float*)d_in[1];
    const float* v    = (const float*)d_in[2];
    const int*   mask = (const int*)  d_in[4];
    const float* Wq   = (const float*)d_in[5];
    const float* bq   = (const float*)d_in[6];
    const float* Wk   = (const float*)d_in[7];
    const float* bk   = (const float*)d_in[8];
    const float* Wv   = (const float*)d_in[9];
    const float* bv   = (const float*)d_in[10];
    const float* Wo   = (const float*)d_in[11];
    const float* bo   = (const float*)d_in[12];

    float* out0 = (float*)d_out;                       // [2,1023,1024]
    float* att  = out0 + (size_t)2 * SM1 * DMODEL;     // [2,16,1023,1023]

    const size_t NX  = (size_t)2048 * 1024;
    const size_t NW  = (size_t)1024 * 1024;
    const size_t NQH = (size_t)2 * HN * SEQ * DH;
    const size_t NVT = (size_t)2 * HN * DH * 1024;

    __bf16* p2  = (__bf16*)d_ws;
    __bf16* qSh = p2; p2 += NX;  __bf16* qSl = p2; p2 += NX;
    __bf16* kSh = p2; p2 += NX;  __bf16* kSl = p2; p2 += NX;
    __bf16* vSh = p2; p2 += NX;  __bf16* vSl = p2; p2 += NX;
    __bf16* WqTh = p2; p2 += NW; __bf16* WqTl = p2; p2 += NW;
    __bf16* WkTh = p2; p2 += NW; __bf16* WkTl = p2; p2 += NW;
    __bf16* WvTh = p2; p2 += NW; __bf16* WvTl = p2; p2 += NW;
    __bf16* WoTh = p2; p2 += NW; __bf16* WoTl = p2; p2 += NW;
    __bf16* qhh = p2; p2 += NQH; __bf16* qhl = p2; p2 += NQH;
    __bf16* khh = p2; p2 += NQH; __bf16* khl = p2; p2 += NQH;
    __bf16* vth = p2; p2 += NVT; __bf16* vtl = p2; p2 += NVT;
    unsigned int* mbG = (unsigned int*)p2;             // [2046][32]
    __bf16* ctxHi = qSh;
    __bf16* ctxLo = qSl;

    (void)hipMemsetAsync(vth, 0, 2 * NVT * sizeof(__bf16), stream);

    mask_pack_kernel<<<dim3(512), 256, 0, stream>>>(mask, mbG);

    split3_kernel<<<dim3(512, 3), 256, 0, stream>>>(
        q, qSh, qSl, 2048 * 1024 / 8,
        k, kSh, kSl, 2048 * 1024 / 8,
        v, vSh, vSl, 2046 * 1024 / 8);

    splitT4_kernel<<<dim3(16, 16, 4), 256, 0, stream>>>(
        Wq, WqTh, WqTl, Wk, WkTh, WkTl, Wv, WvTh, WvTl, Wo, WoTh, WoTl);

    gemm_bf16_kernel<0><<<dim3(16, 32), 256, 0, stream>>>(qSh, qSl, WqTh, WqTl, bq,
                                                          nullptr, qhh, qhl, 2 * SEQ, SEQ);
    gemm_bf16_kernel<0><<<dim3(16, 32), 256, 0, stream>>>(kSh, kSl, WkTh, WkTl, bk,
                                                          nullptr, khh, khl, 2 * SEQ, SEQ);
    gemm_bf16_kernel<2><<<dim3(16, 32), 256, 0, stream>>>(vSh, vSl, WvTh, WvTl, bv,
                                                          nullptr, vth, vtl, 2 * SM1, SM1);

    attn_fused_kernel<<<dim3(512), 512, 0, stream>>>(qhh, qhl, khh, khl, vth, vtl,
                                                     mbG, att, ctxHi, ctxLo);

    gemm_bf16_kernel<1><<<dim3(16, 32), 256, 0, stream>>>(ctxHi, ctxLo, WoTh, WoTl, bo,
                                                          out0, nullptr, nullptr, 2 * SM1, SM1);
}

// Round 21
// 222.796 us; speedup vs baseline: 1.4529x; 1.0214x over previous
//
#include <hip/hip_runtime.h>
#include <math.h>

#define HN 16
#define SEQ 1024
#define DMODEL 1024
#define DH 64
#define SM1 1023   // S-1

typedef float  f32x4  __attribute__((ext_vector_type(4)));
typedef __bf16 bf16x8 __attribute__((ext_vector_type(8)));

// async global->LDS DMA, 16B per lane, dest = wave-uniform base + lane*16
#define GLD16(gsrc, ldst) \
    __builtin_amdgcn_global_load_lds((const __attribute__((address_space(1))) void*)(gsrc), \
                                     (__attribute__((address_space(3))) void*)(ldst), 16, 0, 0)

// ---------------------------------------------------------------
// split3m: fp32 -> bf16 hi/lo planes for q,k,v + mask bitpack,
// all in one launch (blockIdx.y selects; y==3 = mask pack).
// ---------------------------------------------------------------
__global__ __launch_bounds__(256)
void split3m_kernel(const float* __restrict__ s0, __bf16* __restrict__ h0, __bf16* __restrict__ l0, int n0,
                    const float* __restrict__ s1, __bf16* __restrict__ h1, __bf16* __restrict__ l1, int n1,
                    const float* __restrict__ s2, __bf16* __restrict__ h2, __bf16* __restrict__ l2, int n2,
                    const int* __restrict__ mask, unsigned int* __restrict__ mb)
{
    if (blockIdx.y == 3) {
        // mask pack: wave per row, 512 blocks x 4 waves covers 2046 rows
        const int row = blockIdx.x * 4 + (threadIdx.x >> 6);
        const int l   = threadIdx.x & 63;
        if (row >= 2 * SM1) return;
        const int* mrow = mask + (size_t)row * SM1;
        unsigned int* out = mb + (size_t)row * 32;
#pragma unroll
        for (int i = 0; i < 16; ++i) {
            const int c = i * 64 + l;
            const bool mv = (c < SM1) && (mrow[c] != 0);
            unsigned long long bal = __ballot(mv);
            if (l == 0) {
                out[i * 2]     = (unsigned int)bal;
                out[i * 2 + 1] = (unsigned int)(bal >> 32);
            }
        }
        return;
    }

    const float* src; __bf16* hi; __bf16* lo; int nchunks;
    if (blockIdx.y == 0)      { src = s0; hi = h0; lo = l0; nchunks = n0; }
    else if (blockIdx.y == 1) { src = s1; hi = h1; lo = l1; nchunks = n1; }
    else                      { src = s2; hi = h2; lo = l2; nchunks = n2; }

    for (int i = blockIdx.x * 256 + threadIdx.x; i < nchunks; i += gridDim.x * 256) {
        float4 v0 = *(const float4*)&src[(size_t)i * 8];
        float4 v1 = *(const float4*)&src[(size_t)i * 8 + 4];
        float xa[8] = {v0.x, v0.y, v0.z, v0.w, v1.x, v1.y, v1.z, v1.w};
        bf16x8 h8, l8;
#pragma unroll
        for (int e = 0; e < 8; ++e) {
            __bf16 hb = (__bf16)xa[e];
            h8[e] = hb;
            l8[e] = (__bf16)(xa[e] - (float)hb);
        }
        *(bf16x8*)&hi[(size_t)i * 8] = h8;
        *(bf16x8*)&lo[(size_t)i * 8] = l8;
    }
}

// ---------------------------------------------------------------
// splitT4: W[1024][1024] fp32 -> transposed hi/lo planes, 4 weights.
// ---------------------------------------------------------------
__global__ __launch_bounds__(256)
void splitT4_kernel(const float* __restrict__ W0, __bf16* __restrict__ th0, __bf16* __restrict__ tl0,
                    const float* __restrict__ W1, __bf16* __restrict__ th1, __bf16* __restrict__ tl1,
                    const float* __restrict__ W2, __bf16* __restrict__ th2, __bf16* __restrict__ tl2,
                    const float* __restrict__ W3, __bf16* __restrict__ th3, __bf16* __restrict__ tl3)
{
    const float* W; __bf16* thi; __bf16* tlo;
    const int z = blockIdx.z;
    if (z == 0)      { W = W0; thi = th0; tlo = tl0; }
    else if (z == 1) { W = W1; thi = th1; tlo = tl1; }
    else if (z == 2) { W = W2; thi = th2; tlo = tl2; }
    else             { W = W3; thi = th3; tlo = tl3; }

    __shared__ float T[64][65];
    const int t = threadIdx.x;
    const int r0 = blockIdx.y * 64, c0 = blockIdx.x * 64;
#pragma unroll
    for (int it = 0; it < 4; ++it) {
        const int rl = (t >> 4) + it * 16;
        const int cl = (t & 15) * 4;
        float4 v = *(const float4*)&W[(size_t)(r0 + rl) * 1024 + c0 + cl];
        T[cl + 0][rl] = v.x; T[cl + 1][rl] = v.y;
        T[cl + 2][rl] = v.z; T[cl + 3][rl] = v.w;
    }
    __syncthreads();
    const int nl = t >> 2, ch = t & 3;
    float vals[16];
#pragma unroll
    for (int e = 0; e < 16; ++e) vals[e] = T[nl][ch * 16 + e];
    bf16x8 h0, h1, l0, l1;
#pragma unroll
    for (int e = 0; e < 8; ++e) {
        __bf16 hb = (__bf16)vals[e];
        h0[e] = hb; l0[e] = (__bf16)(vals[e] - (float)hb);
        __bf16 hb2 = (__bf16)vals[8 + e];
        h1[e] = hb2; l1[e] = (__bf16)(vals[8 + e] - (float)hb2);
    }
    const size_t base = (size_t)(c0 + nl) * 1024 + r0 + ch * 16;
    *(bf16x8*)&thi[base] = h0; *(bf16x8*)&thi[base + 8] = h1;
    *(bf16x8*)&tlo[base] = l0; *(bf16x8*)&tlo[base + 8] = l1;
}

// ---------------------------------------------------------------
// All-bf16 MFMA GEMM: 64x64 tile, BK=32, DMA-staged double-buffered
// LDS, hoisted per-lane source pointers, 1 barrier/K-step.
// MODE 0: head-split bf16 hi/lo planes out[bh][s(SEQ)][64]
//         (DUAL=1: blockIdx.z selects operand set A2/B2 -> out2)
// MODE 1: plain fp32 out[m][1024]
// MODE 2: transposed bf16 hi/lo planes out[bh][dh][1024]
// ---------------------------------------------------------------
template<int MODE, int DUAL>
__global__ __launch_bounds__(256)
void gemm_bf16_kernel(const __bf16* __restrict__ Ahi, const __bf16* __restrict__ Alo,
                      const __bf16* __restrict__ Bhi, const __bf16* __restrict__ Blo,
                      const float* __restrict__ bias, float* __restrict__ out32,
                      __bf16* __restrict__ outHi, __bf16* __restrict__ outLo,
                      const __bf16* __restrict__ A2hi, const __bf16* __restrict__ A2lo,
                      const __bf16* __restrict__ B2hi, const __bf16* __restrict__ B2lo,
                      const float* __restrict__ bias2,
                      __bf16* __restrict__ out2Hi, __bf16* __restrict__ out2Lo,
                      int M, int rows)
{
    __shared__ __align__(16) char LB[32768];   // As[2]@0/8192, Bs[2]@16384/24576

    if (DUAL && blockIdx.z == 1) {
        Ahi = A2hi; Alo = A2lo; Bhi = B2hi; Blo = B2lo;
        bias = bias2; outHi = out2Hi; outLo = out2Lo;
    }

    const int t = threadIdx.x, w = t >> 6, l = t & 63;
    const int lr = l & 15, ls = l >> 4;
    const int m0 = blockIdx.y * 64, n0 = blockIdx.x * 64;

    f32x4 acc[4];
#pragma unroll
    for (int ct = 0; ct < 4; ++ct) acc[ct] = f32x4{0.f, 0.f, 0.f, 0.f};

    const int ar   = w * 16 + lr;
    const int a_hi = ar * 128 + (((2 * ls    ) ^ (ar & 7)) << 4);
    const int a_lo = ar * 128 + (((2 * ls + 1) ^ (ar & 7)) << 4);

    const __bf16* aA[2];
    const __bf16* bB[2];
#pragma unroll
    for (int i = 0; i < 2; ++i) {
        const int r = (w * 2 + i) * 8 + (l >> 3);
        const int un = (l & 7) ^ (r & 7);
        aA[i] = ((un & 1) ? Alo : Ahi) + (size_t)(m0 + r) * 1024 + (un >> 1) * 8;
        bB[i] = ((un & 1) ? Blo : Bhi) + (size_t)(n0 + r) * 1024 + (un >> 1) * 8;
    }

#define GSTAGE(k0_, buf_) {                                                       \
    _Pragma("unroll")                                                             \
    for (int i_ = 0; i_ < 2; ++i_) {                                              \
        GLD16(aA[i_] + (k0_), LB + (buf_) * 8192 + (w * 2 + i_) * 1024);          \
        GLD16(bB[i_] + (k0_), LB + 16384 + (buf_) * 8192 + (w * 2 + i_) * 1024);  \
    } }

    GSTAGE(0, 0);
    __syncthreads();

    for (int ks = 0; ks < 32; ++ks) {
        const int cur = ks & 1;
        if (ks < 31) GSTAGE((ks + 1) * 32, cur ^ 1);

        const char* As = LB + cur * 8192;
        const char* Bs = LB + 16384 + cur * 8192;
        const bf16x8 ah = *(const bf16x8*)(As + a_hi);
        const bf16x8 al = *(const bf16x8*)(As + a_lo);
        __builtin_amdgcn_s_setprio(1);
#pragma unroll
        for (int ct = 0; ct < 4; ++ct) {
            const int bc   = ct * 16 + lr;
            const int b_hi = bc * 128 + (((2 * ls    ) ^ (bc & 7)) << 4);
            const int b_lo = bc * 128 + (((2 * ls + 1) ^ (bc & 7)) << 4);
            const bf16x8 bh = *(const bf16x8*)(Bs + b_hi);
            const bf16x8 bl = *(const bf16x8*)(Bs + b_lo);
            acc[ct] = __builtin_amdgcn_mfma_f32_16x16x32_bf16(ah, bh, acc[ct], 0, 0, 0);
            acc[ct] = __builtin_amdgcn_mfma_f32_16x16x32_bf16(al, bh, acc[ct], 0, 0, 0);
            acc[ct] = __builtin_amdgcn_mfma_f32_16x16x32_bf16(ah, bl, acc[ct], 0, 0, 0);
        }
        __builtin_amdgcn_s_setprio(0);
        __syncthreads();
    }
#undef GSTAGE

    if (MODE == 2) {
        float* T = (float*)LB;   // [64][65]
#pragma unroll
        for (int ct = 0; ct < 4; ++ct) {
            const int nl = ct * 16 + lr;
            const float bv = bias[n0 + nl];
#pragma unroll
            for (int j = 0; j < 4; ++j)
                T[nl * 65 + w * 16 + ls * 4 + j] = acc[ct][j] + bv;
        }
        __syncthreads();
        const int dr = t >> 2, ch = t & 3;
        const int hh = n0 >> 6;
        const int mb = m0 + ch * 16;
        float vals[16];
#pragma unroll
        for (int e = 0; e < 16; ++e) vals[e] = T[dr * 65 + ch * 16 + e];
        const int bb0 = mb / rows;
        const int s0  = mb - bb0 * rows;
        if (mb + 15 < M && bb0 == (mb + 15) / rows && (s0 & 7) == 0) {
            bf16x8 h0, h1, l0, l1;
#pragma unroll
            for (int e = 0; e < 8; ++e) {
                __bf16 hb = (__bf16)vals[e];
                h0[e] = hb; l0[e] = (__bf16)(vals[e] - (float)hb);
                __bf16 hb2 = (__bf16)vals[8 + e];
                h1[e] = hb2; l1[e] = (__bf16)(vals[8 + e] - (float)hb2);
            }
            const size_t base = (((size_t)(bb0 * HN + hh) * DH + dr) << 10) + s0;
            *(bf16x8*)&outHi[base] = h0; *(bf16x8*)&outHi[base + 8] = h1;
            *(bf16x8*)&outLo[base] = l0; *(bf16x8*)&outLo[base + 8] = l1;
        } else {
#pragma unroll
            for (int e = 0; e < 16; ++e) {
                const int m = mb + e;
                if (m < M) {
                    const int bb = m / rows, s = m - bb * rows;
                    const size_t idx = (((size_t)(bb * HN + hh) * DH + dr) << 10) + s;
                    const __bf16 hb = (__bf16)vals[e];
                    outHi[idx] = hb;
                    outLo[idx] = (__bf16)(vals[e] - (float)hb);
                }
            }
        }
    } else {
#pragma unroll
        for (int ct = 0; ct < 4; ++ct) {
            const int n = n0 + ct * 16 + lr;
            const float bv = bias[n];
#pragma unroll
            for (int j = 0; j < 4; ++j) {
                const int m = m0 + w * 16 + ls * 4 + j;
                if (m >= M) continue;
                const float val = acc[ct][j] + bv;
                if (MODE == 1) {
                    out32[(size_t)m * DMODEL + n] = val;
                } else {
                    const int bb = m / rows, s = m - bb * rows;
                    const __bf16 hb = (__bf16)val;
                    const __bf16 lb = (__bf16)(val - (float)hb);
                    const size_t idx = (((size_t)(bb * HN + (n >> 6)) * SEQ + s) << 6) + (n & 63);
                    outHi[idx] = hb; outLo[idx] = lb;
                }
            }
        }
    }
}

// ---------------------------------------------------------------
// Fused attention (R18/R20 best structure, unchanged).
// ---------------------------------------------------------------
__global__ __launch_bounds__(512, 4)
void attn_fused_kernel(const __bf16* __restrict__ qhi, const __bf16* __restrict__ qlo,
                       const __bf16* __restrict__ khi, const __bf16* __restrict__ klo,
                       const __bf16* __restrict__ vthi, const __bf16* __restrict__ vtlo,
                       const unsigned int* __restrict__ mbG,
                       float* __restrict__ att,
                       __bf16* __restrict__ ctxHi, __bf16* __restrict__ ctxLo)
{
    __shared__ __align__(16) char QE[17408];        // Q 16KB / E[64][68] f32 / red[64][68]
    __shared__ __align__(16) char Kb[2][16384];
    __shared__ __align__(16) char Vb[16384];
    __shared__ unsigned int mbitsT[32][64];
    __shared__ float invs[64];
    __shared__ float partial[64][2];

    const int id  = blockIdx.x;
    const int xcd = id & 7, slot = id >> 3;
    const int bh  = xcd + 8 * (slot >> 4);
    const int b   = bh >> 4, h = bh & 15;
    const int q0  = (slot & 15) * 64;

    const int t = threadIdx.x, w = t >> 6, l = t & 63;
    const int lr = l & 15, ls = l >> 4;
    const int g = w & 3, p = w >> 2;

    // ---- hoisted per-lane DMA source pointers ----
    const __bf16* kA[2];
    const __bf16* vA[2];
#pragma unroll
    for (int i = 0; i < 2; ++i) {
        const int seg = w * 2 + i;
        const int r  = seg * 4 + (l >> 4);
        const int cw = (l & 15) ^ (r & 15);
        kA[i] = ((cw >> 3) ? klo : khi) + ((size_t)bh * SEQ + r) * DH + (cw & 7) * 8;
        vA[i] = ((cw >> 3) ? vtlo : vthi) + (((size_t)bh * DH + r) << 10) + (cw & 7) * 8;
    }

#define KDMA(koff_, b_) {                                                       \
    _Pragma("unroll")                                                           \
    for (int i_ = 0; i_ < 2; ++i_)                                              \
        GLD16(kA[i_] + (koff_), Kb[b_] + (w * 2 + i_) * 1024);                  \
    }
#define VDMA(coff_) {                                                           \
    _Pragma("unroll")                                                           \
    for (int i_ = 0; i_ < 2; ++i_)                                              \
        GLD16(vA[i_] + (coff_), Vb + (w * 2 + i_) * 1024);                      \
    }

    // ---- prologue: Q DMA + K(0) DMA + mask bits ----
#pragma unroll
    for (int i = 0; i < 2; ++i) {
        const int seg = w * 2 + i;
        const int r = seg * 4 + (l >> 4);
        const int cw = (l & 15) ^ (r & 15);
        int qrow = q0 + r + 1; if (qrow > 1023) qrow = 1023;
        const __bf16* src = ((cw >> 3) ? qlo : qhi)
            + ((size_t)bh * SEQ + qrow) * DH + (cw & 7) * 8;
        GLD16(src, QE + seg * 1024);
    }
    KDMA(0, 0);
#pragma unroll
    for (int it = 0; it < 4; ++it) {
        const int idm = t + it * 512;
        const int cw = idm & 31, r = idm >> 5;
        const int rr = q0 + r;
        mbitsT[cw][r] = (rr < SM1) ? mbG[((size_t)b * SM1 + rr) * 32 + cw] : 0u;
    }
    __syncthreads();

    const int arow = g * 16 + lr;
    const bf16x8 a0h = *(const bf16x8*)(QE + arow * 256 + (((ls     ) ^ lr) << 4));
    const bf16x8 a1h = *(const bf16x8*)(QE + arow * 256 + ((( 4 + ls) ^ lr) << 4));
    const bf16x8 a0l = *(const bf16x8*)(QE + arow * 256 + ((( 8 + ls) ^ lr) << 4));
    const bf16x8 a1l = *(const bf16x8*)(QE + arow * 256 + (((12 + ls) ^ lr) << 4));
    __syncthreads();   // Q area free (becomes E in pass 2)

    // ================= pass 1: row sums of exp =================
    float rsum[4] = {0.f, 0.f, 0.f, 0.f};
    for (int kt = 0; kt < 16; ++kt) {
        const char* KB = Kb[kt & 1];
        if (kt < 15) KDMA((kt + 1) * 4096, (kt + 1) & 1);

#pragma unroll
        for (int i = 0; i < 2; ++i) {
            const int ct = p * 2 + i;
            const int kr16 = ct * 16 + lr;
            const bf16x8 b0h = *(const bf16x8*)(KB + kr16 * 256 + (((ls     ) ^ lr) << 4));
            const bf16x8 b1h = *(const bf16x8*)(KB + kr16 * 256 + ((( 4 + ls) ^ lr) << 4));
            const bf16x8 b0l = *(const bf16x8*)(KB + kr16 * 256 + ((( 8 + ls) ^ lr) << 4));
            const bf16x8 b1l = *(const bf16x8*)(KB + kr16 * 256 + (((12 + ls) ^ lr) << 4));

            f32x4 acc = {0.f, 0.f, 0.f, 0.f};
            __builtin_amdgcn_s_setprio(1);
            acc = __builtin_amdgcn_mfma_f32_16x16x32_bf16(a0h, b0h, acc, 0, 0, 0);
            acc = __builtin_amdgcn_mfma_f32_16x16x32_bf16(a0l, b0h, acc, 0, 0, 0);
            acc = __builtin_amdgcn_mfma_f32_16x16x32_bf16(a0h, b0l, acc, 0, 0, 0);
            acc = __builtin_amdgcn_mfma_f32_16x16x32_bf16(a1h, b1h, acc, 0, 0, 0);
            acc = __builtin_amdgcn_mfma_f32_16x16x32_bf16(a1l, b1h, acc, 0, 0, 0);
            acc = __builtin_amdgcn_mfma_f32_16x16x32_bf16(a1h, b1l, acc, 0, 0, 0);
            __builtin_amdgcn_s_setprio(0);

            const int c = kt * 64 + ct * 16 + lr;
            const int wmi = kt * 2 + (ct >> 1);
#pragma unroll
            for (int j = 0; j < 4; ++j) {
                const int r = q0 + g * 16 + ls * 4 + j;
                if (r < SM1 && c < SM1) {
                    float sc = fmaxf(acc[j] * 0.125f, 0.f);
                    const unsigned int wm = mbitsT[wmi][g * 16 + ls * 4 + j];
                    if ((wm >> ((ct & 1) * 16 + lr)) & 1u) sc = -1e9f;
                    rsum[j] += __expf(sc);
                }
            }
        }
        __syncthreads();
    }

    KDMA(0, 0);   // K(0) for pass 2 (drains under the reduce)

#pragma unroll
    for (int j = 0; j < 4; ++j) {
        rsum[j] += __shfl_xor(rsum[j], 1, 64);
        rsum[j] += __shfl_xor(rsum[j], 2, 64);
        rsum[j] += __shfl_xor(rsum[j], 4, 64);
        rsum[j] += __shfl_xor(rsum[j], 8, 64);
    }
    if (lr == 0) {
#pragma unroll
        for (int j = 0; j < 4; ++j)
            partial[g * 16 + ls * 4 + j][p] = rsum[j];
    }
    __syncthreads();
    if (t < 64) {
        const float s = partial[t][0] + partial[t][1];
        invs[t] = (q0 + t < SM1) ? 1.0f / s : 0.f;
    }
    __syncthreads();
    float inv4[4];
#pragma unroll
    for (int j = 0; j < 4; ++j) inv4[j] = invs[g * 16 + ls * 4 + j];

    // ================= pass 2: weights + PV =================
    float* E = (float*)QE;   // [64][68]
    f32x4 oacc[4];
#pragma unroll
    for (int ct = 0; ct < 4; ++ct) oacc[ct] = f32x4{0.f, 0.f, 0.f, 0.f};

    for (int kt = 0; kt < 16; ++kt) {
        const int c0 = kt * 64;
        const char* KB = Kb[kt & 1];
        VDMA(c0);
        if (kt < 15) KDMA((kt + 1) * 4096, (kt + 1) & 1);

#pragma unroll
        for (int i = 0; i < 2; ++i) {
            const int ct = p * 2 + i;
            const int kr16 = ct * 16 + lr;
            const bf16x8 b0h = *(const bf16x8*)(KB + kr16 * 256 + (((ls     ) ^ lr) << 4));
            const bf16x8 b1h = *(const bf16x8*)(KB + kr16 * 256 + ((( 4 + ls) ^ lr) << 4));
            const bf16x8 b0l = *(const bf16x8*)(KB + kr16 * 256 + ((( 8 + ls) ^ lr) << 4));
            const bf16x8 b1l = *(const bf16x8*)(KB + kr16 * 256 + (((12 + ls) ^ lr) << 4));

            f32x4 acc = {0.f, 0.f, 0.f, 0.f};
            __builtin_amdgcn_s_setprio(1);
            acc = __builtin_amdgcn_mfma_f32_16x16x32_bf16(a0h, b0h, acc, 0, 0, 0);
            acc = __builtin_amdgcn_mfma_f32_16x16x32_bf16(a0l, b0h, acc, 0, 0, 0);
            acc = __builtin_amdgcn_mfma_f32_16x16x32_bf16(a0h, b0l, acc, 0, 0, 0);
            acc = __builtin_amdgcn_mfma_f32_16x16x32_bf16(a1h, b1h, acc, 0, 0, 0);
            acc = __builtin_amdgcn_mfma_f32_16x16x32_bf16(a1l, b1h, acc, 0, 0, 0);
            acc = __builtin_amdgcn_mfma_f32_16x16x32_bf16(a1h, b1l, acc, 0, 0, 0);
            __builtin_amdgcn_s_setprio(0);

            const int c = c0 + ct * 16 + lr;
            const int wmi = kt * 2 + (ct >> 1);
#pragma unroll
            for (int j = 0; j < 4; ++j) {
                const int r = q0 + g * 16 + ls * 4 + j;
                float v = 0.f;
                if (r < SM1 && c < SM1) {
                    float sc = fmaxf(acc[j] * 0.125f, 0.f);
                    const unsigned int wm = mbitsT[wmi][g * 16 + ls * 4 + j];
                    if ((wm >> ((ct & 1) * 16 + lr)) & 1u) sc = -1e9f;
                    v = __expf(sc) * inv4[j];
                }
                E[(g * 16 + ls * 4 + j) * 68 + ct * 16 + lr] = v;
            }
        }
        __syncthreads();   // B: E complete; V (and next K) drained

        // ---- coalesced weight write-out from E (64 rows x 64 cols) ----
#pragma unroll
        for (int it = 0; it < 2; ++it) {
            const int idw = t + it * 512;
            const int r = idw >> 4, q4 = idw & 15;
            const int rr = q0 + r, cc = c0 + q4 * 4;
            if (rr < SM1) {
                f32x4 vv = *(const f32x4*)&E[r * 68 + q4 * 4];
                float* dst = &att[((size_t)bh * SM1 + rr) * SM1 + cc];
                if (cc + 4 <= SM1) {
                    __builtin_nontemporal_store(vv, (f32x4*)dst);
                } else {
                    if (cc + 0 < SM1) dst[0] = vv.x;
                    if (cc + 1 < SM1) dst[1] = vv.y;
                    if (cc + 2 < SM1) dst[2] = vv.z;
                }
            }
        }

        // ---- PV: parity p handles keys p*32..p*32+31 of the tile ----
        {
            const int pr = g * 16 + lr;
            const f32x4 p0 = *(const f32x4*)&E[pr * 68 + p * 32 + ls * 8];
            const f32x4 p1 = *(const f32x4*)&E[pr * 68 + p * 32 + ls * 8 + 4];
            float pf[8] = {p0.x, p0.y, p0.z, p0.w, p1.x, p1.y, p1.z, p1.w};
            bf16x8 ph, pl;
#pragma unroll
            for (int e = 0; e < 8; ++e) {
                const __bf16 hb = (__bf16)pf[e];
                ph[e] = hb;
                pl[e] = (__bf16)(pf[e] - (float)hb);
            }
#pragma unroll
            for (int ct = 0; ct < 4; ++ct) {
                const int vr16 = ct * 16 + lr;
                const bf16x8 vh = *(const bf16x8*)(Vb + vr16 * 256 + (((p * 4 + ls    ) ^ lr) << 4));
                const bf16x8 vl = *(const bf16x8*)(Vb + vr16 * 256 + (((8 + p * 4 + ls) ^ lr) << 4));
                __builtin_amdgcn_s_setprio(1);
                oacc[ct] = __builtin_amdgcn_mfma_f32_16x16x32_bf16(ph, vh, oacc[ct], 0, 0, 0);
                oacc[ct] = __builtin_amdgcn_mfma_f32_16x16x32_bf16(pl, vh, oacc[ct], 0, 0, 0);
                oacc[ct] = __builtin_amdgcn_mfma_f32_16x16x32_bf16(ph, vl, oacc[ct], 0, 0, 0);
                __builtin_amdgcn_s_setprio(0);
            }
        }
        __syncthreads();   // C: PV done -> Vb free, E free
    }

    // ---- cross-parity reduce and ctx hi/lo plane write ----
    float* red = (float*)QE;   // [64][68]
    if (p == 1) {
#pragma unroll
        for (int ct = 0; ct < 4; ++ct)
#pragma unroll
            for (int j = 0; j < 4; ++j)
                red[(g * 16 + ls * 4 + j) * 68 + ct * 16 + lr] = oacc[ct][j];
    }
    __syncthreads();
    if (p == 0) {
#pragma unroll
        for (int ct = 0; ct < 4; ++ct)
#pragma unroll
            for (int j = 0; j < 4; ++j) {
                const int r = q0 + g * 16 + ls * 4 + j;
                if (r < SM1) {
                    const float val =
                        oacc[ct][j] + red[(g * 16 + ls * 4 + j) * 68 + ct * 16 + lr];
                    const size_t idx =
                        ((size_t)b * SM1 + r) * DMODEL + h * DH + ct * 16 + lr;
                    const __bf16 hb = (__bf16)val;
                    ctxHi[idx] = hb;
                    ctxLo[idx] = (__bf16)(val - (float)hb);
                }
            }
    }
#undef KDMA
#undef VDMA
}

// ---------------------------------------------------------------
extern "C" void kernel_launch(void* const* d_in, const int* in_sizes, int n_in,
                              void* d_out, int out_size, void* d_ws, size_t ws_size,
                              hipStream_t stream) {
    const float* q    = (const float*)d_in[0];
    const float* k    = (const float*)d_in[1];
    const float* v    = (const float*)d_in[2];
    const int*   mask = (const int*)  d_in[4];
    const float* Wq   = (const float*)d_in[5];
    const float* bq   = (const float*)d_in[6];
    const float* Wk   = (const float*)d_in[7];
    const float* bk   = (const float*)d_in[8];
    const float* Wv   = (const float*)d_in[9];
    const float* bv   = (const float*)d_in[10];
    const float* Wo   = (const float*)d_in[11];
    const float* bo   = (const float*)d_in[12];

    float* out0 = (float*)d_out;                       // [2,1023,1024]
    float* att  = out0 + (size_t)2 * SM1 * DMODEL;     // [2,16,1023,1023]

    const size_t NX  = (size_t)2048 * 1024;
    const size_t NW  = (size_t)1024 * 1024;
    const size_t NQH = (size_t)2 * HN * SEQ * DH;
    const size_t NVT = (size_t)2 * HN * DH * 1024;

    __bf16* p2  = (__bf16*)d_ws;
    __bf16* qSh = p2; p2 += NX;  __bf16* qSl = p2; p2 += NX;
    __bf16* kSh = p2; p2 += NX;  __bf16* kSl = p2; p2 += NX;
    __bf16* vSh = p2; p2 += NX;  __bf16* vSl = p2; p2 += NX;
    __bf16* WqTh = p2; p2 += NW; __bf16* WqTl = p2; p2 += NW;
    __bf16* WkTh = p2; p2 += NW; __bf16* WkTl = p2; p2 += NW;
    __bf16* WvTh = p2; p2 += NW; __bf16* WvTl = p2; p2 += NW;
    __bf16* WoTh = p2; p2 += NW; __bf16* WoTl = p2; p2 += NW;
    __bf16* qhh = p2; p2 += NQH; __bf16* qhl = p2; p2 += NQH;
    __bf16* khh = p2; p2 += NQH; __bf16* khl = p2; p2 += NQH;
    __bf16* vth = p2; p2 += NVT; __bf16* vtl = p2; p2 += NVT;
    unsigned int* mbG = (unsigned int*)p2;             // [2046][32]
    __bf16* ctxHi = qSh;
    __bf16* ctxLo = qSl;

    (void)hipMemsetAsync(vth, 0, 2 * NVT * sizeof(__bf16), stream);

    split3m_kernel<<<dim3(512, 4), 256, 0, stream>>>(
        q, qSh, qSl, 2048 * 1024 / 8,
        k, kSh, kSl, 2048 * 1024 / 8,
        v, vSh, vSl, 2046 * 1024 / 8,
        mask, mbG);

    splitT4_kernel<<<dim3(16, 16, 4), 256, 0, stream>>>(
        Wq, WqTh, WqTl, Wk, WkTh, WkTl, Wv, WvTh, WvTl, Wo, WoTh, WoTl);

    // Q and K projections in one launch (blockIdx.z selects)
    gemm_bf16_kernel<0, 1><<<dim3(16, 32, 2), 256, 0, stream>>>(
        qSh, qSl, WqTh, WqTl, bq, nullptr, qhh, qhl,
        kSh, kSl, WkTh, WkTl, bk, khh, khl, 2 * SEQ, SEQ);

    gemm_bf16_kernel<2, 0><<<dim3(16, 32), 256, 0, stream>>>(
        vSh, vSl, WvTh, WvTl, bv, nullptr, vth, vtl,
        nullptr, nullptr, nullptr, nullptr, nullptr, nullptr, nullptr, 2 * SM1, SM1);

    attn_fused_kernel<<<dim3(512), 512, 0, stream>>>(qhh, qhl, khh, khl, vth, vtl,
                                                     mbG, att, ctxHi, ctxLo);

    gemm_bf16_kernel<1, 0><<<dim3(16, 32), 256, 0, stream>>>(
        ctxHi, ctxLo, WoTh, WoTl, bo, out0, nullptr, nullptr,
        nullptr, nullptr, nullptr, nullptr, nullptr, nullptr, nullptr, 2 * SM1, SM1);
}

// Round 22
// 222.008 us; speedup vs baseline: 1.4580x; 1.0035x over previous
//
#include <hip/hip_runtime.h>
#include <math.h>

#define HN 16
#define SEQ 1024
#define DMODEL 1024
#define DH 64
#define SM1 1023   // S-1

typedef float  f32x4  __attribute__((ext_vector_type(4)));
typedef __bf16 bf16x8 __attribute__((ext_vector_type(8)));

// async global->LDS DMA, 16B per lane, dest = wave-uniform base + lane*16
#define GLD16(gsrc, ldst) \
    __builtin_amdgcn_global_load_lds((const __attribute__((address_space(1))) void*)(gsrc), \
                                     (__attribute__((address_space(3))) void*)(ldst), 16, 0, 0)

// ---------------------------------------------------------------
// prep: fp32->bf16 hi/lo split for q,k,v + mask bitpack + 4 weight
// transposes, all in ONE launch. Flat 3072-block grid:
//   id in [0,2048): split/mask (y=id>>9: 0..2=q/k/v, 3=mask)
//   id in [2048,3072): weight transpose (z=(id-2048)>>8, 16x16 tiles)
// ---------------------------------------------------------------
__global__ __launch_bounds__(256)
void prep_kernel(const float* __restrict__ s0, __bf16* __restrict__ h0, __bf16* __restrict__ l0, int n0,
                 const float* __restrict__ s1, __bf16* __restrict__ h1, __bf16* __restrict__ l1, int n1,
                 const float* __restrict__ s2, __bf16* __restrict__ h2, __bf16* __restrict__ l2, int n2,
                 const int* __restrict__ mask, unsigned int* __restrict__ mb,
                 const float* __restrict__ W0, __bf16* __restrict__ th0, __bf16* __restrict__ tl0,
                 const float* __restrict__ W1, __bf16* __restrict__ th1, __bf16* __restrict__ tl1,
                 const float* __restrict__ W2, __bf16* __restrict__ th2, __bf16* __restrict__ tl2,
                 const float* __restrict__ W3, __bf16* __restrict__ th3, __bf16* __restrict__ tl3)
{
    const int bid = blockIdx.x;
    if (bid < 2048) {
        const int by = bid >> 9, bx = bid & 511;
        if (by == 3) {
            // mask pack: wave per row
            const int row = bx * 4 + (threadIdx.x >> 6);
            const int l   = threadIdx.x & 63;
            if (row >= 2 * SM1) return;
            const int* mrow = mask + (size_t)row * SM1;
            unsigned int* out = mb + (size_t)row * 32;
#pragma unroll
            for (int i = 0; i < 16; ++i) {
                const int c = i * 64 + l;
                const bool mv = (c < SM1) && (mrow[c] != 0);
                unsigned long long bal = __ballot(mv);
                if (l == 0) {
                    out[i * 2]     = (unsigned int)bal;
                    out[i * 2 + 1] = (unsigned int)(bal >> 32);
                }
            }
            return;
        }
        const float* src; __bf16* hi; __bf16* lo; int nchunks;
        if (by == 0)      { src = s0; hi = h0; lo = l0; nchunks = n0; }
        else if (by == 1) { src = s1; hi = h1; lo = l1; nchunks = n1; }
        else              { src = s2; hi = h2; lo = l2; nchunks = n2; }

        for (int i = bx * 256 + threadIdx.x; i < nchunks; i += 512 * 256) {
            float4 v0 = *(const float4*)&src[(size_t)i * 8];
            float4 v1 = *(const float4*)&src[(size_t)i * 8 + 4];
            float xa[8] = {v0.x, v0.y, v0.z, v0.w, v1.x, v1.y, v1.z, v1.w};
            bf16x8 h8, l8;
#pragma unroll
            for (int e = 0; e < 8; ++e) {
                __bf16 hb = (__bf16)xa[e];
                h8[e] = hb;
                l8[e] = (__bf16)(xa[e] - (float)hb);
            }
            *(bf16x8*)&hi[(size_t)i * 8] = h8;
            *(bf16x8*)&lo[(size_t)i * 8] = l8;
        }
        return;
    }

    // ---- weight transpose+split path ----
    const int idT = bid - 2048;
    const int z = idT >> 8, by = (idT >> 4) & 15, bx = idT & 15;
    const float* W; __bf16* thi; __bf16* tlo;
    if (z == 0)      { W = W0; thi = th0; tlo = tl0; }
    else if (z == 1) { W = W1; thi = th1; tlo = tl1; }
    else if (z == 2) { W = W2; thi = th2; tlo = tl2; }
    else             { W = W3; thi = th3; tlo = tl3; }

    __shared__ float T[64][65];
    const int t = threadIdx.x;
    const int r0 = by * 64, c0 = bx * 64;
#pragma unroll
    for (int it = 0; it < 4; ++it) {
        const int rl = (t >> 4) + it * 16;
        const int cl = (t & 15) * 4;
        float4 v = *(const float4*)&W[(size_t)(r0 + rl) * 1024 + c0 + cl];
        T[cl + 0][rl] = v.x; T[cl + 1][rl] = v.y;
        T[cl + 2][rl] = v.z; T[cl + 3][rl] = v.w;
    }
    __syncthreads();
    const int nl = t >> 2, ch = t & 3;
    float vals[16];
#pragma unroll
    for (int e = 0; e < 16; ++e) vals[e] = T[nl][ch * 16 + e];
    bf16x8 h0v, h1v, l0v, l1v;
#pragma unroll
    for (int e = 0; e < 8; ++e) {
        __bf16 hb = (__bf16)vals[e];
        h0v[e] = hb; l0v[e] = (__bf16)(vals[e] - (float)hb);
        __bf16 hb2 = (__bf16)vals[8 + e];
        h1v[e] = hb2; l1v[e] = (__bf16)(vals[8 + e] - (float)hb2);
    }
    const size_t base = (size_t)(c0 + nl) * 1024 + r0 + ch * 16;
    *(bf16x8*)&thi[base] = h0v; *(bf16x8*)&thi[base + 8] = h1v;
    *(bf16x8*)&tlo[base] = l0v; *(bf16x8*)&tlo[base + 8] = l1v;
}

// ---------------------------------------------------------------
// All-bf16 MFMA GEMM: 64x64 tile, BK=32, DMA-staged double-buffered
// LDS, hoisted per-lane source pointers, 1 barrier/K-step.
// MODE 0: head-split bf16 hi/lo planes out[bh][s(SEQ)][64]
//         (DUAL=1: blockIdx.z selects operand set A2/B2 -> out2)
// MODE 1: plain fp32 out[m][1024]
// MODE 2: transposed bf16 hi/lo planes out[bh][dh][1024]
// ---------------------------------------------------------------
template<int MODE, int DUAL>
__global__ __launch_bounds__(256)
void gemm_bf16_kernel(const __bf16* __restrict__ Ahi, const __bf16* __restrict__ Alo,
                      const __bf16* __restrict__ Bhi, const __bf16* __restrict__ Blo,
                      const float* __restrict__ bias, float* __restrict__ out32,
                      __bf16* __restrict__ outHi, __bf16* __restrict__ outLo,
                      const __bf16* __restrict__ A2hi, const __bf16* __restrict__ A2lo,
                      const __bf16* __restrict__ B2hi, const __bf16* __restrict__ B2lo,
                      const float* __restrict__ bias2,
                      __bf16* __restrict__ out2Hi, __bf16* __restrict__ out2Lo,
                      int M, int rows)
{
    __shared__ __align__(16) char LB[32768];   // As[2]@0/8192, Bs[2]@16384/24576

    if (DUAL && blockIdx.z == 1) {
        Ahi = A2hi; Alo = A2lo; Bhi = B2hi; Blo = B2lo;
        bias = bias2; outHi = out2Hi; outLo = out2Lo;
    }

    const int t = threadIdx.x, w = t >> 6, l = t & 63;
    const int lr = l & 15, ls = l >> 4;
    const int m0 = blockIdx.y * 64, n0 = blockIdx.x * 64;

    f32x4 acc[4];
#pragma unroll
    for (int ct = 0; ct < 4; ++ct) acc[ct] = f32x4{0.f, 0.f, 0.f, 0.f};

    const int ar   = w * 16 + lr;
    const int a_hi = ar * 128 + (((2 * ls    ) ^ (ar & 7)) << 4);
    const int a_lo = ar * 128 + (((2 * ls + 1) ^ (ar & 7)) << 4);

    const __bf16* aA[2];
    const __bf16* bB[2];
#pragma unroll
    for (int i = 0; i < 2; ++i) {
        const int r = (w * 2 + i) * 8 + (l >> 3);
        const int un = (l & 7) ^ (r & 7);
        aA[i] = ((un & 1) ? Alo : Ahi) + (size_t)(m0 + r) * 1024 + (un >> 1) * 8;
        bB[i] = ((un & 1) ? Blo : Bhi) + (size_t)(n0 + r) * 1024 + (un >> 1) * 8;
    }

#define GSTAGE(k0_, buf_) {                                                       \
    _Pragma("unroll")                                                             \
    for (int i_ = 0; i_ < 2; ++i_) {                                              \
        GLD16(aA[i_] + (k0_), LB + (buf_) * 8192 + (w * 2 + i_) * 1024);          \
        GLD16(bB[i_] + (k0_), LB + 16384 + (buf_) * 8192 + (w * 2 + i_) * 1024);  \
    } }

    GSTAGE(0, 0);
    __syncthreads();

    for (int ks = 0; ks < 32; ++ks) {
        const int cur = ks & 1;
        if (ks < 31) GSTAGE((ks + 1) * 32, cur ^ 1);

        const char* As = LB + cur * 8192;
        const char* Bs = LB + 16384 + cur * 8192;
        const bf16x8 ah = *(const bf16x8*)(As + a_hi);
        const bf16x8 al = *(const bf16x8*)(As + a_lo);
        __builtin_amdgcn_s_setprio(1);
#pragma unroll
        for (int ct = 0; ct < 4; ++ct) {
            const int bc   = ct * 16 + lr;
            const int b_hi = bc * 128 + (((2 * ls    ) ^ (bc & 7)) << 4);
            const int b_lo = bc * 128 + (((2 * ls + 1) ^ (bc & 7)) << 4);
            const bf16x8 bh = *(const bf16x8*)(Bs + b_hi);
            const bf16x8 bl = *(const bf16x8*)(Bs + b_lo);
            acc[ct] = __builtin_amdgcn_mfma_f32_16x16x32_bf16(ah, bh, acc[ct], 0, 0, 0);
            acc[ct] = __builtin_amdgcn_mfma_f32_16x16x32_bf16(al, bh, acc[ct], 0, 0, 0);
            acc[ct] = __builtin_amdgcn_mfma_f32_16x16x32_bf16(ah, bl, acc[ct], 0, 0, 0);
        }
        __builtin_amdgcn_s_setprio(0);
        __syncthreads();
    }
#undef GSTAGE

    if (MODE == 2) {
        float* T = (float*)LB;   // [64][65]
#pragma unroll
        for (int ct = 0; ct < 4; ++ct) {
            const int nl = ct * 16 + lr;
            const float bv = bias[n0 + nl];
#pragma unroll
            for (int j = 0; j < 4; ++j)
                T[nl * 65 + w * 16 + ls * 4 + j] = acc[ct][j] + bv;
        }
        __syncthreads();
        const int dr = t >> 2, ch = t & 3;
        const int hh = n0 >> 6;
        const int mb = m0 + ch * 16;
        float vals[16];
#pragma unroll
        for (int e = 0; e < 16; ++e) vals[e] = T[dr * 65 + ch * 16 + e];
        const int bb0 = mb / rows;
        const int s0  = mb - bb0 * rows;
        if (mb + 15 < M && bb0 == (mb + 15) / rows && (s0 & 7) == 0) {
            bf16x8 h0, h1, l0, l1;
#pragma unroll
            for (int e = 0; e < 8; ++e) {
                __bf16 hb = (__bf16)vals[e];
                h0[e] = hb; l0[e] = (__bf16)(vals[e] - (float)hb);
                __bf16 hb2 = (__bf16)vals[8 + e];
                h1[e] = hb2; l1[e] = (__bf16)(vals[8 + e] - (float)hb2);
            }
            const size_t base = (((size_t)(bb0 * HN + hh) * DH + dr) << 10) + s0;
            *(bf16x8*)&outHi[base] = h0; *(bf16x8*)&outHi[base + 8] = h1;
            *(bf16x8*)&outLo[base] = l0; *(bf16x8*)&outLo[base + 8] = l1;
        } else {
#pragma unroll
            for (int e = 0; e < 16; ++e) {
                const int m = mb + e;
                if (m < M) {
                    const int bb = m / rows, s = m - bb * rows;
                    const size_t idx = (((size_t)(bb * HN + hh) * DH + dr) << 10) + s;
                    const __bf16 hb = (__bf16)vals[e];
                    outHi[idx] = hb;
                    outLo[idx] = (__bf16)(vals[e] - (float)hb);
                }
            }
        }
    } else {
#pragma unroll
        for (int ct = 0; ct < 4; ++ct) {
            const int n = n0 + ct * 16 + lr;
            const float bv = bias[n];
#pragma unroll
            for (int j = 0; j < 4; ++j) {
                const int m = m0 + w * 16 + ls * 4 + j;
                if (m >= M) continue;
                const float val = acc[ct][j] + bv;
                if (MODE == 1) {
                    out32[(size_t)m * DMODEL + n] = val;
                } else {
                    const int bb = m / rows, s = m - bb * rows;
                    const __bf16 hb = (__bf16)val;
                    const __bf16 lb = (__bf16)(val - (float)hb);
                    const size_t idx = (((size_t)(bb * HN + (n >> 6)) * SEQ + s) << 6) + (n & 63);
                    outHi[idx] = hb; outLo[idx] = lb;
                }
            }
        }
    }
}

// ---------------------------------------------------------------
// Fused attention (R18/R20 best structure, unchanged).
// ---------------------------------------------------------------
__global__ __launch_bounds__(512, 4)
void attn_fused_kernel(const __bf16* __restrict__ qhi, const __bf16* __restrict__ qlo,
                       const __bf16* __restrict__ khi, const __bf16* __restrict__ klo,
                       const __bf16* __restrict__ vthi, const __bf16* __restrict__ vtlo,
                       const unsigned int* __restrict__ mbG,
                       float* __restrict__ att,
                       __bf16* __restrict__ ctxHi, __bf16* __restrict__ ctxLo)
{
    __shared__ __align__(16) char QE[17408];        // Q 16KB / E[64][68] f32 / red[64][68]
    __shared__ __align__(16) char Kb[2][16384];
    __shared__ __align__(16) char Vb[16384];
    __shared__ unsigned int mbitsT[32][64];
    __shared__ float invs[64];
    __shared__ float partial[64][2];

    const int id  = blockIdx.x;
    const int xcd = id & 7, slot = id >> 3;
    const int bh  = xcd + 8 * (slot >> 4);
    const int b   = bh >> 4, h = bh & 15;
    const int q0  = (slot & 15) * 64;

    const int t = threadIdx.x, w = t >> 6, l = t & 63;
    const int lr = l & 15, ls = l >> 4;
    const int g = w & 3, p = w >> 2;

    // ---- hoisted per-lane DMA source pointers ----
    const __bf16* kA[2];
    const __bf16* vA[2];
#pragma unroll
    for (int i = 0; i < 2; ++i) {
        const int seg = w * 2 + i;
        const int r  = seg * 4 + (l >> 4);
        const int cw = (l & 15) ^ (r & 15);
        kA[i] = ((cw >> 3) ? klo : khi) + ((size_t)bh * SEQ + r) * DH + (cw & 7) * 8;
        vA[i] = ((cw >> 3) ? vtlo : vthi) + (((size_t)bh * DH + r) << 10) + (cw & 7) * 8;
    }

#define KDMA(koff_, b_) {                                                       \
    _Pragma("unroll")                                                           \
    for (int i_ = 0; i_ < 2; ++i_)                                              \
        GLD16(kA[i_] + (koff_), Kb[b_] + (w * 2 + i_) * 1024);                  \
    }
#define VDMA(coff_) {                                                           \
    _Pragma("unroll")                                                           \
    for (int i_ = 0; i_ < 2; ++i_)                                              \
        GLD16(vA[i_] + (coff_), Vb + (w * 2 + i_) * 1024);                      \
    }

    // ---- prologue: Q DMA + K(0) DMA + mask bits ----
#pragma unroll
    for (int i = 0; i < 2; ++i) {
        const int seg = w * 2 + i;
        const int r = seg * 4 + (l >> 4);
        const int cw = (l & 15) ^ (r & 15);
        int qrow = q0 + r + 1; if (qrow > 1023) qrow = 1023;
        const __bf16* src = ((cw >> 3) ? qlo : qhi)
            + ((size_t)bh * SEQ + qrow) * DH + (cw & 7) * 8;
        GLD16(src, QE + seg * 1024);
    }
    KDMA(0, 0);
#pragma unroll
    for (int it = 0; it < 4; ++it) {
        const int idm = t + it * 512;
        const int cw = idm & 31, r = idm >> 5;
        const int rr = q0 + r;
        mbitsT[cw][r] = (rr < SM1) ? mbG[((size_t)b * SM1 + rr) * 32 + cw] : 0u;
    }
    __syncthreads();

    const int arow = g * 16 + lr;
    const bf16x8 a0h = *(const bf16x8*)(QE + arow * 256 + (((ls     ) ^ lr) << 4));
    const bf16x8 a1h = *(const bf16x8*)(QE + arow * 256 + ((( 4 + ls) ^ lr) << 4));
    const bf16x8 a0l = *(const bf16x8*)(QE + arow * 256 + ((( 8 + ls) ^ lr) << 4));
    const bf16x8 a1l = *(const bf16x8*)(QE + arow * 256 + (((12 + ls) ^ lr) << 4));
    __syncthreads();   // Q area free (becomes E in pass 2)

    // ================= pass 1: row sums of exp =================
    float rsum[4] = {0.f, 0.f, 0.f, 0.f};
    for (int kt = 0; kt < 16; ++kt) {
        const char* KB = Kb[kt & 1];
        if (kt < 15) KDMA((kt + 1) * 4096, (kt + 1) & 1);

#pragma unroll
        for (int i = 0; i < 2; ++i) {
            const int ct = p * 2 + i;
            const int kr16 = ct * 16 + lr;
            const bf16x8 b0h = *(const bf16x8*)(KB + kr16 * 256 + (((ls     ) ^ lr) << 4));
            const bf16x8 b1h = *(const bf16x8*)(KB + kr16 * 256 + ((( 4 + ls) ^ lr) << 4));
            const bf16x8 b0l = *(const bf16x8*)(KB + kr16 * 256 + ((( 8 + ls) ^ lr) << 4));
            const bf16x8 b1l = *(const bf16x8*)(KB + kr16 * 256 + (((12 + ls) ^ lr) << 4));

            f32x4 acc = {0.f, 0.f, 0.f, 0.f};
            __builtin_amdgcn_s_setprio(1);
            acc = __builtin_amdgcn_mfma_f32_16x16x32_bf16(a0h, b0h, acc, 0, 0, 0);
            acc = __builtin_amdgcn_mfma_f32_16x16x32_bf16(a0l, b0h, acc, 0, 0, 0);
            acc = __builtin_amdgcn_mfma_f32_16x16x32_bf16(a0h, b0l, acc, 0, 0, 0);
            acc = __builtin_amdgcn_mfma_f32_16x16x32_bf16(a1h, b1h, acc, 0, 0, 0);
            acc = __builtin_amdgcn_mfma_f32_16x16x32_bf16(a1l, b1h, acc, 0, 0, 0);
            acc = __builtin_amdgcn_mfma_f32_16x16x32_bf16(a1h, b1l, acc, 0, 0, 0);
            __builtin_amdgcn_s_setprio(0);

            const int c = kt * 64 + ct * 16 + lr;
            const int wmi = kt * 2 + (ct >> 1);
#pragma unroll
            for (int j = 0; j < 4; ++j) {
                const int r = q0 + g * 16 + ls * 4 + j;
                if (r < SM1 && c < SM1) {
                    float sc = fmaxf(acc[j] * 0.125f, 0.f);
                    const unsigned int wm = mbitsT[wmi][g * 16 + ls * 4 + j];
                    if ((wm >> ((ct & 1) * 16 + lr)) & 1u) sc = -1e9f;
                    rsum[j] += __expf(sc);
                }
            }
        }
        __syncthreads();
    }

    KDMA(0, 0);   // K(0) for pass 2 (drains under the reduce)

#pragma unroll
    for (int j = 0; j < 4; ++j) {
        rsum[j] += __shfl_xor(rsum[j], 1, 64);
        rsum[j] += __shfl_xor(rsum[j], 2, 64);
        rsum[j] += __shfl_xor(rsum[j], 4, 64);
        rsum[j] += __shfl_xor(rsum[j], 8, 64);
    }
    if (lr == 0) {
#pragma unroll
        for (int j = 0; j < 4; ++j)
            partial[g * 16 + ls * 4 + j][p] = rsum[j];
    }
    __syncthreads();
    if (t < 64) {
        const float s = partial[t][0] + partial[t][1];
        invs[t] = (q0 + t < SM1) ? 1.0f / s : 0.f;
    }
    __syncthreads();
    float inv4[4];
#pragma unroll
    for (int j = 0; j < 4; ++j) inv4[j] = invs[g * 16 + ls * 4 + j];

    // ================= pass 2: weights + PV =================
    float* E = (float*)QE;   // [64][68]
    f32x4 oacc[4];
#pragma unroll
    for (int ct = 0; ct < 4; ++ct) oacc[ct] = f32x4{0.f, 0.f, 0.f, 0.f};

    for (int kt = 0; kt < 16; ++kt) {
        const int c0 = kt * 64;
        const char* KB = Kb[kt & 1];
        VDMA(c0);
        if (kt < 15) KDMA((kt + 1) * 4096, (kt + 1) & 1);

#pragma unroll
        for (int i = 0; i < 2; ++i) {
            const int ct = p * 2 + i;
            const int kr16 = ct * 16 + lr;
            const bf16x8 b0h = *(const bf16x8*)(KB + kr16 * 256 + (((ls     ) ^ lr) << 4));
            const bf16x8 b1h = *(const bf16x8*)(KB + kr16 * 256 + ((( 4 + ls) ^ lr) << 4));
            const bf16x8 b0l = *(const bf16x8*)(KB + kr16 * 256 + ((( 8 + ls) ^ lr) << 4));
            const bf16x8 b1l = *(const bf16x8*)(KB + kr16 * 256 + (((12 + ls) ^ lr) << 4));

            f32x4 acc = {0.f, 0.f, 0.f, 0.f};
            __builtin_amdgcn_s_setprio(1);
            acc = __builtin_amdgcn_mfma_f32_16x16x32_bf16(a0h, b0h, acc, 0, 0, 0);
            acc = __builtin_amdgcn_mfma_f32_16x16x32_bf16(a0l, b0h, acc, 0, 0, 0);
            acc = __builtin_amdgcn_mfma_f32_16x16x32_bf16(a0h, b0l, acc, 0, 0, 0);
            acc = __builtin_amdgcn_mfma_f32_16x16x32_bf16(a1h, b1h, acc, 0, 0, 0);
            acc = __builtin_amdgcn_mfma_f32_16x16x32_bf16(a1l, b1h, acc, 0, 0, 0);
            acc = __builtin_amdgcn_mfma_f32_16x16x32_bf16(a1h, b1l, acc, 0, 0, 0);
            __builtin_amdgcn_s_setprio(0);

            const int c = c0 + ct * 16 + lr;
            const int wmi = kt * 2 + (ct >> 1);
#pragma unroll
            for (int j = 0; j < 4; ++j) {
                const int r = q0 + g * 16 + ls * 4 + j;
                float v = 0.f;
                if (r < SM1 && c < SM1) {
                    float sc = fmaxf(acc[j] * 0.125f, 0.f);
                    const unsigned int wm = mbitsT[wmi][g * 16 + ls * 4 + j];
                    if ((wm >> ((ct & 1) * 16 + lr)) & 1u) sc = -1e9f;
                    v = __expf(sc) * inv4[j];
                }
                E[(g * 16 + ls * 4 + j) * 68 + ct * 16 + lr] = v;
            }
        }
        __syncthreads();   // B: E complete; V (and next K) drained

        // ---- coalesced weight write-out from E (64 rows x 64 cols) ----
#pragma unroll
        for (int it = 0; it < 2; ++it) {
            const int idw = t + it * 512;
            const int r = idw >> 4, q4 = idw & 15;
            const int rr = q0 + r, cc = c0 + q4 * 4;
            if (rr < SM1) {
                f32x4 vv = *(const f32x4*)&E[r * 68 + q4 * 4];
                float* dst = &att[((size_t)bh * SM1 + rr) * SM1 + cc];
                if (cc + 4 <= SM1) {
                    __builtin_nontemporal_store(vv, (f32x4*)dst);
                } else {
                    if (cc + 0 < SM1) dst[0] = vv.x;
                    if (cc + 1 < SM1) dst[1] = vv.y;
                    if (cc + 2 < SM1) dst[2] = vv.z;
                }
            }
        }

        // ---- PV: parity p handles keys p*32..p*32+31 of the tile ----
        {
            const int pr = g * 16 + lr;
            const f32x4 p0 = *(const f32x4*)&E[pr * 68 + p * 32 + ls * 8];
            const f32x4 p1 = *(const f32x4*)&E[pr * 68 + p * 32 + ls * 8 + 4];
            float pf[8] = {p0.x, p0.y, p0.z, p0.w, p1.x, p1.y, p1.z, p1.w};
            bf16x8 ph, pl;
#pragma unroll
            for (int e = 0; e < 8; ++e) {
                const __bf16 hb = (__bf16)pf[e];
                ph[e] = hb;
                pl[e] = (__bf16)(pf[e] - (float)hb);
            }
#pragma unroll
            for (int ct = 0; ct < 4; ++ct) {
                const int vr16 = ct * 16 + lr;
                const bf16x8 vh = *(const bf16x8*)(Vb + vr16 * 256 + (((p * 4 + ls    ) ^ lr) << 4));
                const bf16x8 vl = *(const bf16x8*)(Vb + vr16 * 256 + (((8 + p * 4 + ls) ^ lr) << 4));
                __builtin_amdgcn_s_setprio(1);
                oacc[ct] = __builtin_amdgcn_mfma_f32_16x16x32_bf16(ph, vh, oacc[ct], 0, 0, 0);
                oacc[ct] = __builtin_amdgcn_mfma_f32_16x16x32_bf16(pl, vh, oacc[ct], 0, 0, 0);
                oacc[ct] = __builtin_amdgcn_mfma_f32_16x16x32_bf16(ph, vl, oacc[ct], 0, 0, 0);
                __builtin_amdgcn_s_setprio(0);
            }
        }
        __syncthreads();   // C: PV done -> Vb free, E free
    }

    // ---- cross-parity reduce and ctx hi/lo plane write ----
    float* red = (float*)QE;   // [64][68]
    if (p == 1) {
#pragma unroll
        for (int ct = 0; ct < 4; ++ct)
#pragma unroll
            for (int j = 0; j < 4; ++j)
                red[(g * 16 + ls * 4 + j) * 68 + ct * 16 + lr] = oacc[ct][j];
    }
    __syncthreads();
    if (p == 0) {
#pragma unroll
        for (int ct = 0; ct < 4; ++ct)
#pragma unroll
            for (int j = 0; j < 4; ++j) {
                const int r = q0 + g * 16 + ls * 4 + j;
                if (r < SM1) {
                    const float val =
                        oacc[ct][j] + red[(g * 16 + ls * 4 + j) * 68 + ct * 16 + lr];
                    const size_t idx =
                        ((size_t)b * SM1 + r) * DMODEL + h * DH + ct * 16 + lr;
                    const __bf16 hb = (__bf16)val;
                    ctxHi[idx] = hb;
                    ctxLo[idx] = (__bf16)(val - (float)hb);
                }
            }
    }
#undef KDMA
#undef VDMA
}

// ---------------------------------------------------------------
extern "C" void kernel_launch(void* const* d_in, const int* in_sizes, int n_in,
                              void* d_out, int out_size, void* d_ws, size_t ws_size,
                              hipStream_t stream) {
    const float* q    = (const float*)d_in[0];
    const float* k    = (const float*)d_in[1];
    const float* v    = (const float*)d_in[2];
    const int*   mask = (const int*)  d_in[4];
    const float* Wq   = (const float*)d_in[5];
    const float* bq   = (const float*)d_in[6];
    const float* Wk   = (const float*)d_in[7];
    const float* bk   = (const float*)d_in[8];
    const float* Wv   = (const float*)d_in[9];
    const float* bv   = (const float*)d_in[10];
    const float* Wo   = (const float*)d_in[11];
    const float* bo   = (const float*)d_in[12];

    float* out0 = (float*)d_out;                       // [2,1023,1024]
    float* att  = out0 + (size_t)2 * SM1 * DMODEL;     // [2,16,1023,1023]

    const size_t NX  = (size_t)2048 * 1024;
    const size_t NW  = (size_t)1024 * 1024;
    const size_t NQH = (size_t)2 * HN * SEQ * DH;
    const size_t NVT = (size_t)2 * HN * DH * 1024;

    __bf16* p2  = (__bf16*)d_ws;
    __bf16* qSh = p2; p2 += NX;  __bf16* qSl = p2; p2 += NX;
    __bf16* kSh = p2; p2 += NX;  __bf16* kSl = p2; p2 += NX;
    __bf16* vSh = p2; p2 += NX;  __bf16* vSl = p2; p2 += NX;
    __bf16* WqTh = p2; p2 += NW; __bf16* WqTl = p2; p2 += NW;
    __bf16* WkTh = p2; p2 += NW; __bf16* WkTl = p2; p2 += NW;
    __bf16* WvTh = p2; p2 += NW; __bf16* WvTl = p2; p2 += NW;
    __bf16* WoTh = p2; p2 += NW; __bf16* WoTl = p2; p2 += NW;
    __bf16* qhh = p2; p2 += NQH; __bf16* qhl = p2; p2 += NQH;
    __bf16* khh = p2; p2 += NQH; __bf16* khl = p2; p2 += NQH;
    __bf16* vth = p2; p2 += NVT; __bf16* vtl = p2; p2 += NVT;
    unsigned int* mbG = (unsigned int*)p2;             // [2046][32]
    __bf16* ctxHi = qSh;
    __bf16* ctxLo = qSl;

    (void)hipMemsetAsync(vth, 0, 2 * NVT * sizeof(__bf16), stream);

    prep_kernel<<<dim3(3072), 256, 0, stream>>>(
        q, qSh, qSl, 2048 * 1024 / 8,
        k, kSh, kSl, 2048 * 1024 / 8,
        v, vSh, vSl, 2046 * 1024 / 8,
        mask, mbG,
        Wq, WqTh, WqTl, Wk, WkTh, WkTl, Wv, WvTh, WvTl, Wo, WoTh, WoTl);

    // Q and K projections in one launch (blockIdx.z selects)
    gemm_bf16_kernel<0, 1><<<dim3(16, 32, 2), 256, 0, stream>>>(
        qSh, qSl, WqTh, WqTl, bq, nullptr, qhh, qhl,
        kSh, kSl, WkTh, WkTl, bk, khh, khl, 2 * SEQ, SEQ);

    gemm_bf16_kernel<2, 0><<<dim3(16, 32), 256, 0, stream>>>(
        vSh, vSl, WvTh, WvTl, bv, nullptr, vth, vtl,
        nullptr, nullptr, nullptr, nullptr, nullptr, nullptr, nullptr, 2 * SM1, SM1);

    attn_fused_kernel<<<dim3(512), 512, 0, stream>>>(qhh, qhl, khh, khl, vth, vtl,
                                                     mbG, att, ctxHi, ctxLo);

    gemm_bf16_kernel<1, 0><<<dim3(16, 32), 256, 0, stream>>>(
        ctxHi, ctxLo, WoTh, WoTl, bo, out0, nullptr, nullptr,
        nullptr, nullptr, nullptr, nullptr, nullptr, nullptr, nullptr, 2 * SM1, SM1);
}